// Round 2
// baseline (268.109 us; speedup 1.0000x reference)
//
#include <hip/hip_runtime.h>
#include <hip/hip_fp16.h>

#define CIN 32
#define COUT 32
#define KK 9
#define PIX 65536          // 256*256 input pixels
#define OH 512
#define OW 512
#define OHOW (OH*OW)
#define NCH 64             // B*COUT
#define TW 16              // tile width  (x)
#define TH 4               // tile height (y)
#define TPX (TW*TH)        // 64 px per tile
#define NTX (OW/TW)        // 32
#define NTY (OH/TH)        // 128
#define NTILE (NTX*NTY)    // 4096
#define NBIN NTILE         // per-TILE bins now (was per-stripe)
#define NPK (PIX*KK)       // 589824 (p,k) pairs
#define ECAP 1500000       // ~784K entries expected at tile granularity; ~2x headroom

// ---- ws layout (bytes) ----
#define OFF_CNT 0                              // u32[NBIN]    16 KB
#define OFF_OFF (128*1024)                     // u32[NBIN+1]
#define OFF_CUR (256*1024)                     // u32[NBIN]
#define OFF_WT  (384*1024)                     // bf16 hi[9216] + lo[9216] = 36.9 KB
#define OFF_ENT (512*1024)                     // uint2[ECAP]  12 MB
#define OFF_CB  (OFF_ENT + (size_t)ECAP*8)     // f16[NPK*64] 75.5 MB
#define WS_NEED (OFF_CB + (size_t)NPK*NCH*2)   // ~88.0 MB

typedef __bf16    bf16x8 __attribute__((ext_vector_type(8)));
typedef _Float16  f16x8  __attribute__((ext_vector_type(8)));
typedef float     f32x4  __attribute__((ext_vector_type(4)));

__device__ __forceinline__ unsigned short f2h(float v)
{
    return __half_as_ushort(__float2half_rn(v));
}

// corner setup (clips never fire for this input; kept for safety)
__device__ __forceinline__ void corners(float sx, float sy,
    int& x0, int& y0, int& x1, int& y1, float& dx, float& dy)
{
    const float x0f = floorf(sx), y0f = floorf(sy);
    dx = sx - x0f; dy = sy - y0f;
    x0 = min(max((int)x0f, 0), OW - 1);
    y0 = min(max((int)y0f, 0), OH - 1);
    x1 = min(x0 + 1, OW - 1);
    y1 = min(y0 + 1, OH - 1);
}

// ============ pass 0: W[i][o][k] -> bf16 hi/lo [k][o][i] =====================
__global__ __launch_bounds__(256) void k_wtb(
    const float* __restrict__ w, __bf16* __restrict__ wth, __bf16* __restrict__ wtl)
{
    const int t = blockIdx.x * 256 + threadIdx.x;   // (k*32+o)*32 + i
    if (t < KK * COUT * CIN) {
        const int i = t & 31;
        const int o = (t >> 5) & 31;
        const int k = t >> 10;
        const float v = w[(i * COUT + o) * KK + k];
        const __bf16 h = (__bf16)v;
        wth[t] = h;
        wtl[t] = (__bf16)(v - (float)h);
    }
}

// ============ pass 1: contrib[p][k][ch] f16 via MFMA =========================
// (same structure as round-1; output now f16 for better gather precision)
__global__ __launch_bounds__(256, 4) void k_contrib2(
    const float* __restrict__ x, const __bf16* __restrict__ wth,
    const __bf16* __restrict__ wtl, const float* __restrict__ smap,
    unsigned short* __restrict__ cb, unsigned* __restrict__ cnt)
{
    __shared__ __align__(16) unsigned short slice[2][64][68];  // 17 KB, 34-dword rows
    const int tid = threadIdx.x, lane = tid & 63;
    const int wu = __builtin_amdgcn_readfirstlane(tid >> 6);   // uniform wave id
    const int p0 = blockIdx.x * 64;

    // ---- fused count: per-TILE bins, 576 (p,k) items ----
    {
        const int i0 = p0 * KK;
        for (int it = tid; it < 576; it += 256) {
            const int t = i0 + it;
            const float sx = smap[2 * t], sy = smap[2 * t + 1];
            int x0, y0, x1, y1; float dx, dy;
            corners(sx, sy, x0, y0, x1, y1, dx, dy);
            const int g0 = x0 >> 4, g1 = x1 >> 4;   // tile col
            const int t0 = y0 >> 2, t1 = y1 >> 2;   // tile row
            atomicAdd(&cnt[t0 * 32 + g0], 1u);
            if (g1 != g0) atomicAdd(&cnt[t0 * 32 + g1], 1u);
            if (t1 != t0) {
                atomicAdd(&cnt[t1 * 32 + g0], 1u);
                if (g1 != g0) atomicAdd(&cnt[t1 * 32 + g1], 1u);
            }
        }
    }

    // ---- per-lane x fragments (B-operand): 8 ci x 4 px-groups, hi/lo bf16 ----
    const int b = wu >> 1;
    const int obase = (wu & 1) * 16;
    const int colp = lane & 15;          // px column within 16-px group
    const int cig  = (lane >> 4) * 8;    // ci base for this lane's k-chunk
    bf16x8 xh[4], xl[4];
    #pragma unroll
    for (int m = 0; m < 4; ++m) {
        const int p = p0 + m * 16 + colp;
        #pragma unroll
        for (int j = 0; j < 8; ++j) {
            const float v = x[(size_t)(b * 32 + cig + j) * PIX + p];
            const __bf16 h = (__bf16)v;
            xh[m][j] = h;
            xl[m][j] = (__bf16)(v - (float)h);
        }
    }

    unsigned* cbd = (unsigned*)cb;                  // dword view of cb
    const int wo = ((obase + colp) << 5) + cig;     // o*32 + ci within a k-slab
    const int ch0 = b * 32 + obase + ((lane >> 4) << 2);

    for (int k = 0; k < KK; ++k) {
        const int buf = k & 1;
        const bf16x8 wh = *(const bf16x8*)(wth + k * (COUT * CIN) + wo);
        const bf16x8 wl = *(const bf16x8*)(wtl + k * (COUT * CIN) + wo);
        #pragma unroll
        for (int m = 0; m < 4; ++m) {
            f32x4 a = {0.f, 0.f, 0.f, 0.f};
            a = __builtin_amdgcn_mfma_f32_16x16x32_bf16(wh, xh[m], a, 0, 0, 0);
            a = __builtin_amdgcn_mfma_f32_16x16x32_bf16(wl, xh[m], a, 0, 0, 0);
            a = __builtin_amdgcn_mfma_f32_16x16x32_bf16(wh, xl[m], a, 0, 0, 0);
            const unsigned d0 = (unsigned)f2h(a[0]) | ((unsigned)f2h(a[1]) << 16);
            const unsigned d1 = (unsigned)f2h(a[2]) | ((unsigned)f2h(a[3]) << 16);
            const int px = m * 16 + colp;
            *(uint2*)&slice[buf][px][ch0] = make_uint2(d0, d1);
        }
        __syncthreads();
        {
            const int r = tid >> 2, chunk = tid & 3;
            const unsigned* src = (const unsigned*)&slice[buf][r][0] + chunk * 8;
            unsigned v0 = src[0], v1 = src[1], v2 = src[2], v3 = src[3];
            unsigned v4 = src[4], v5 = src[5], v6 = src[6], v7 = src[7];
            unsigned* dst = cbd + (size_t)(p0 + r) * 288 + k * 32 + chunk * 8;
            *(uint4*)dst       = make_uint4(v0, v1, v2, v3);
            *(uint4*)(dst + 4) = make_uint4(v4, v5, v6, v7);
        }
    }
}

// ============ pass 3: exclusive scan of 4096 counters (1 block) ==============
__global__ __launch_bounds__(1024) void k_scan(
    const unsigned* __restrict__ cnt, unsigned* __restrict__ off,
    unsigned* __restrict__ cur)
{
    __shared__ unsigned s[1024];
    const int tid = threadIdx.x;
    unsigned c[4]; unsigned sum = 0;
    const int base = tid * 4;
    #pragma unroll
    for (int j = 0; j < 4; ++j) { c[j] = cnt[base + j]; sum += c[j]; }
    s[tid] = sum; __syncthreads();
    unsigned val = sum;
    for (int d = 1; d < 1024; d <<= 1) {
        const unsigned v = (tid >= d) ? s[tid - d] : 0u;
        __syncthreads();
        val += v; s[tid] = val;
        __syncthreads();
    }
    unsigned run = val - sum;
    #pragma unroll
    for (int j = 0; j < 4; ++j) { off[base + j] = run; cur[base + j] = run; run += c[j]; }
    if (tid == 1023) off[NBIN] = run;
}

// ============ pass 4: fill self-contained records (per-tile bins) ============
// record.x = rowIdx(20b) | (lx0+1)<<20 (5b) | (ly0+1)<<25 (3b)  [tile-relative]
// record.y = f16(dx) | f16(dy)<<16
__global__ __launch_bounds__(256) void k_fill(
    const float* __restrict__ smap, unsigned* __restrict__ cur,
    uint2* __restrict__ ent)
{
    const int t = blockIdx.x * 256 + threadIdx.x;
    if (t >= NPK) return;
    const float sx = smap[2 * t], sy = smap[2 * t + 1];
    int x0, y0, x1, y1; float dx, dy;
    corners(sx, sy, x0, y0, x1, y1, dx, dy);
    const int g0 = x0 >> 4, g1 = x1 >> 4;
    const int t0 = y0 >> 2, t1 = y1 >> 2;
    const unsigned w1 = (unsigned)f2h(dx) | ((unsigned)f2h(dy) << 16);
    const unsigned rowIdx = (unsigned)t;
    unsigned slot;
    #define EMIT(ty, gs) { \
        const unsigned lxb = (unsigned)(x0 - (gs) * TW + 1); \
        const unsigned lyb = (unsigned)(y0 - (ty) * TH + 1); \
        slot = atomicAdd(&cur[(ty) * 32 + (gs)], 1u); \
        if (slot < ECAP) ent[slot] = make_uint2(rowIdx | (lxb << 20) | (lyb << 25), w1); }
    EMIT(t0, g0);
    if (g1 != g0) EMIT(t0, g1);
    if (t1 != t0) {
        EMIT(t1, g0);
        if (g1 != g0) EMIT(t1, g1);
    }
    #undef EMIT
}

// ============ pass 5: batched-MFMA gather ====================================
// Per tile (64 px), per 64-entry batch: densify W[px][e] (f16, XOR-swizzled)
// + stage CV[ch][e] from cb; out[px][ch] += W x CV via 16x16x32 f16 MFMA.
// Double-buffered build/compute; accs in registers; LDS-transposed epilogue.
__global__ __launch_bounds__(256, 4) void k_gather(
    const unsigned short* __restrict__ cb, const uint2* __restrict__ ent,
    const unsigned* __restrict__ off, const float* __restrict__ bias,
    float* __restrict__ out)
{
    __shared__ __align__(16) unsigned char smem[32768];
    // W  buf b: smem + b*8192          : f16 [64px][64e], e XOR-swizzled by px&7
    // CV buf b: smem + 16384 + b*8192  : f16 [64ch][64e], e XOR-swizzled by ch&7
    // epilogue: f32 stage[64][65] reuses smem[0..16640)
    const int tid = threadIdx.x, lane = tid & 63;
    const int wv = __builtin_amdgcn_readfirstlane(tid >> 6);   // wave id 0..3
    const int bt = blockIdx.x;
    const int tx0 = (bt & 31) * TW;
    const int ty0 = (bt >> 5) * TH;

    const unsigned s0 = min(off[bt], (unsigned)ECAP);
    const unsigned s1 = min(off[bt + 1], (unsigned)ECAP);
    const int nb = (int)(s1 - s0 + 63) >> 6;

    f32x4 acc[4] = {{0.f,0.f,0.f,0.f},{0.f,0.f,0.f,0.f},
                    {0.f,0.f,0.f,0.f},{0.f,0.f,0.f,0.f}};

    for (int it = 0; it <= nb; ++it) {
        const int bb = it & 1;
        unsigned short* Wb = (unsigned short*)(smem + bb * 8192);
        unsigned short* Cv = (unsigned short*)(smem + 16384 + bb * 8192);
        if (it < nb) {                              // zero W (8 KB)
            uint4* wq = (uint4*)Wb;
            const uint4 z = make_uint4(0u, 0u, 0u, 0u);
            wq[tid] = z; wq[tid + 256] = z;
        }
        __syncthreads();   // zero visible; prior MFMA done reading buf bb
        if (it < nb) {
            // ---- scatter bilinear weights: thread = (entry, corner) ----
            {
                const int eL = tid >> 2, cn = tid & 3;
                const unsigned e = s0 + (unsigned)(it * 64 + eL);
                if (e < s1) {
                    const uint2 r = ent[e];
                    const int lx = (int)((r.x >> 20) & 31) - 1 + (cn & 1);
                    const int ly = (int)((r.x >> 25) & 7) - 1 + (cn >> 1);
                    if (((unsigned)lx < TW) & ((unsigned)ly < TH)) {
                        const float dx = __half2float(__ushort_as_half((unsigned short)(r.y & 0xFFFF)));
                        const float dy = __half2float(__ushort_as_half((unsigned short)(r.y >> 16)));
                        const float wx = (cn & 1) ? dx : 1.f - dx;
                        const float wy = (cn >> 1) ? dy : 1.f - dy;
                        const int px = ly * TW + lx;
                        Wb[px * 64 + (eL ^ ((px & 7) << 3))] = f2h(wx * wy);
                    }
                }
            }
            // ---- stage CV rows: wave wv handles entries [wv*16, wv*16+16) ----
            {
                unsigned short u[16];
                #pragma unroll
                for (int j = 0; j < 16; ++j) {
                    const unsigned e = s0 + (unsigned)(it * 64 + wv * 16 + j);
                    unsigned short v = 0;
                    if (e < s1) {
                        const unsigned row = ent[e].x & 0xFFFFFu;
                        v = cb[((size_t)row << 6) + lane];
                    }
                    u[j] = v;
                }
                uint4* cvq = (uint4*)Cv;
                const uint4 pk0 = make_uint4(
                    (unsigned)u[0]  | ((unsigned)u[1]  << 16),
                    (unsigned)u[2]  | ((unsigned)u[3]  << 16),
                    (unsigned)u[4]  | ((unsigned)u[5]  << 16),
                    (unsigned)u[6]  | ((unsigned)u[7]  << 16));
                const uint4 pk1 = make_uint4(
                    (unsigned)u[8]  | ((unsigned)u[9]  << 16),
                    (unsigned)u[10] | ((unsigned)u[11] << 16),
                    (unsigned)u[12] | ((unsigned)u[13] << 16),
                    (unsigned)u[14] | ((unsigned)u[15] << 16));
                cvq[lane * 8 + ((wv * 2)     ^ (lane & 7))] = pk0;
                cvq[lane * 8 + ((wv * 2 + 1) ^ (lane & 7))] = pk1;
            }
        }
        if (it > 0) {
            // ---- MFMA on previous buffer: out[16px x 64ch] += W x CV ----
            const int pb = bb ^ 1;
            const unsigned short* Wp = (const unsigned short*)(smem + pb * 8192);
            const unsigned short* Cp = (const unsigned short*)(smem + 16384 + pb * 8192);
            const int m = lane & 15, kh = lane >> 4;
            const int px = wv * 16 + m;
            f16x8 af[2];
            #pragma unroll
            for (int kc = 0; kc < 2; ++kc)
                af[kc] = *(const f16x8*)(Wp + px * 64 + (((kc * 4 + kh) ^ (px & 7)) << 3));
            #pragma unroll
            for (int n = 0; n < 4; ++n) {
                const int ch = n * 16 + m;
                #pragma unroll
                for (int kc = 0; kc < 2; ++kc) {
                    const f16x8 bf = *(const f16x8*)(Cp + ch * 64 + (((kc * 4 + kh) ^ (ch & 7)) << 3));
                    acc[n] = __builtin_amdgcn_mfma_f32_16x16x32_f16(af[kc], bf, acc[n], 0, 0, 0);
                }
            }
        }
        __syncthreads();   // build of buf bb complete; MFMA of bb^1 done
    }

    // ---- epilogue: transpose through LDS, coalesced store ----
    float* stage = (float*)smem;
    #pragma unroll
    for (int n = 0; n < 4; ++n) {
        #pragma unroll
        for (int r = 0; r < 4; ++r)
            stage[(wv * 16 + (lane >> 4) * 4 + r) * 65 + n * 16 + (lane & 15)] = acc[n][r];
    }
    __syncthreads();
    const int py = lane >> 4, pxx = lane & 15;
    const size_t q = (size_t)(ty0 + py) * OW + tx0 + pxx;
    #pragma unroll
    for (int j = 0; j < 16; ++j) {
        const int c = wv * 16 + j;
        out[(size_t)c * OHOW + q] = stage[(py * 16 + pxx) * 65 + c] + bias[c & 31];
    }
}

// ================= fallback (round-1 path, no ws requirement) ================
__global__ __launch_bounds__(576) void mtc_scatter_direct(
    const float* __restrict__ x, const float* __restrict__ weight,
    const float* __restrict__ smap, float* __restrict__ acc)
{
    __shared__ float xs[64][68];
    __shared__ float sm[64 * KK * 2];
    const int t = threadIdx.x;
    const int p0 = blockIdx.x * 64;
    if (t < 512) {
        const int pp = t & 63, c0 = t >> 6;
        #pragma unroll
        for (int ch = 0; ch < 8; ++ch) {
            const int c = c0 + ch * 8;
            xs[pp][c] = x[(size_t)c * PIX + p0 + pp];
        }
    }
    for (int i = t; i < 64 * KK * 2; i += 576)
        sm[i] = smap[(size_t)p0 * (KK * 2) + i];
    const int k = t >> 6, lane = t & 63, b = lane >> 5, o = lane & 31;
    float wreg[CIN];
    #pragma unroll
    for (int i = 0; i < CIN; ++i) wreg[i] = weight[(i * COUT + o) * KK + k];
    __syncthreads();
    for (int pp = 0; pp < 64; ++pp) {
        const float sx = sm[(pp * KK + k) * 2], sy = sm[(pp * KK + k) * 2 + 1];
        int x0, y0, x1, y1; float dx, dy;
        corners(sx, sy, x0, y0, x1, y1, dx, dy);
        const float* xrow = &xs[pp][b * 32];
        float cv = 0.f;
        #pragma unroll
        for (int j = 0; j < 8; ++j) {
            const float4 xv = *(const float4*)(xrow + 4 * j);
            cv += xv.x * wreg[4*j] + xv.y * wreg[4*j+1] + xv.z * wreg[4*j+2] + xv.w * wreg[4*j+3];
        }
        const size_t base = (size_t)lane * OHOW;
        atomicAdd(&acc[base + y0 * OW + x0], cv * (1.f - dx) * (1.f - dy));
        atomicAdd(&acc[base + y0 * OW + x1], cv * dx * (1.f - dy));
        atomicAdd(&acc[base + y1 * OW + x0], cv * (1.f - dx) * dy);
        atomicAdd(&acc[base + y1 * OW + x1], cv * dx * dy);
    }
}

__global__ __launch_bounds__(256) void mtc_bias_add(
    float* __restrict__ out, const float* __restrict__ bias)
{
    const size_t i = (size_t)blockIdx.x * 256 + threadIdx.x;
    out[i] += bias[(i >> 18) & 31];
}

extern "C" void kernel_launch(void* const* d_in, const int* in_sizes, int n_in,
                              void* d_out, int out_size, void* d_ws, size_t ws_size,
                              hipStream_t stream) {
    const float* x      = (const float*)d_in[0];
    const float* weight = (const float*)d_in[1];
    const float* bias   = (const float*)d_in[2];
    const float* smap   = (const float*)d_in[3];
    float* out = (float*)d_out;
    char* ws = (char*)d_ws;

    if (ws_size >= WS_NEED) {
        unsigned* cnt = (unsigned*)(ws + OFF_CNT);
        unsigned* off = (unsigned*)(ws + OFF_OFF);
        unsigned* cur = (unsigned*)(ws + OFF_CUR);
        __bf16* wth   = (__bf16*)(ws + OFF_WT);
        __bf16* wtl   = wth + KK * COUT * CIN;
        uint2* ent    = (uint2*)(ws + OFF_ENT);
        unsigned short* cb = (unsigned short*)(ws + OFF_CB);

        hipMemsetAsync(cnt, 0, NBIN * sizeof(unsigned), stream);
        k_wtb<<<(KK * COUT * CIN + 255) / 256, 256, 0, stream>>>(weight, wth, wtl);
        k_contrib2<<<PIX / 64, 256, 0, stream>>>(x, wth, wtl, smap, cb, cnt);
        k_scan<<<1, 1024, 0, stream>>>(cnt, off, cur);
        k_fill<<<(NPK + 255) / 256, 256, 0, stream>>>(smap, cur, ent);
        k_gather<<<NTILE, 256, 0, stream>>>(cb, ent, off, bias, out);
    } else {
        hipMemsetAsync(out, 0, (size_t)OHOW * NCH * sizeof(float), stream);
        mtc_scatter_direct<<<PIX / 64, 576, 0, stream>>>(x, weight, smap, out);
        mtc_bias_add<<<(OHOW * NCH) / 256, 256, 0, stream>>>(out, bias);
    }
}

// Round 3
// 218.434 us; speedup vs baseline: 1.2274x; 1.2274x over previous
//
#include <hip/hip_runtime.h>
#include <hip/hip_fp16.h>

#define CIN 32
#define COUT 32
#define KK 9
#define PIX 65536          // 256*256 input pixels
#define OH 512
#define OW 512
#define OHOW (OH*OW)
#define NCH 64             // B*COUT
#define TW 16              // tile width  (x)
#define TH 4               // tile height (y)
#define TPX (TW*TH)        // 64 px per tile
#define NTX (OW/TW)        // 32
#define NTY (OH/TH)        // 128
#define NTILE (NTX*NTY)    // 4096
#define NBIN NTILE         // per-tile bins
#define NPK (PIX*KK)       // 589824 (p,k) pairs
#define CAP 384            // fixed bin capacity; lambda=191, P(overflow)~1e-40

// ---- ws layout (bytes) ----
#define OFF_CNT 0                              // u32[NBIN*16] 256 KB (64B-padded counters)
#define OFF_WT  (256*1024)                     // bf16 hi[9216] + lo[9216] = 36.9 KB
#define OFF_ENT (512*1024)                     // uint2[NBIN*CAP]  12.6 MB
#define OFF_CB  (OFF_ENT + (size_t)NBIN*CAP*8) // f16[NPK*64] 75.5 MB
#define WS_NEED (OFF_CB + (size_t)NPK*NCH*2)   // ~88.6 MB (>=90.2 proven to exist)

typedef __bf16    bf16x8 __attribute__((ext_vector_type(8)));
typedef _Float16  f16x8  __attribute__((ext_vector_type(8)));
typedef float     f32x4  __attribute__((ext_vector_type(4)));

__device__ __forceinline__ unsigned short f2h(float v)
{
    return __half_as_ushort(__float2half_rn(v));
}

// corner setup (clips never fire for this input; kept for safety)
__device__ __forceinline__ void corners(float sx, float sy,
    int& x0, int& y0, int& x1, int& y1, float& dx, float& dy)
{
    const float x0f = floorf(sx), y0f = floorf(sy);
    dx = sx - x0f; dy = sy - y0f;
    x0 = min(max((int)x0f, 0), OW - 1);
    y0 = min(max((int)y0f, 0), OH - 1);
    x1 = min(x0 + 1, OW - 1);
    y1 = min(y0 + 1, OH - 1);
}

// ============ pass 0: W[i][o][k] -> bf16 hi/lo [k][o][i] =====================
__global__ __launch_bounds__(256) void k_wtb(
    const float* __restrict__ w, __bf16* __restrict__ wth, __bf16* __restrict__ wtl)
{
    const int t = blockIdx.x * 256 + threadIdx.x;   // (k*32+o)*32 + i
    if (t < KK * COUT * CIN) {
        const int i = t & 31;
        const int o = (t >> 5) & 31;
        const int k = t >> 10;
        const float v = w[(i * COUT + o) * KK + k];
        const __bf16 h = (__bf16)v;
        wth[t] = h;
        wtl[t] = (__bf16)(v - (float)h);
    }
}

// ============ pass 1: contrib via MFMA + fused binning, ZERO barriers ========
// Each block: 64 px. Waves (b, o-half). Per k: 3 hi/lo MFMAs per 16-px group;
// D-fragment = 4 consecutive channels/lane -> direct 8B global store into cb
// (L2 write-back merges the 16 lanes dirtying each 128B row). No LDS, no
// __syncthreads -> no vmcnt(0) drains; atomics + stores are fire-and-forget.
// Fused binning emits self-contained records into fixed-capacity bins.
__global__ __launch_bounds__(256) void k_contrib3(
    const float* __restrict__ x, const __bf16* __restrict__ wth,
    const __bf16* __restrict__ wtl, const float* __restrict__ smap,
    unsigned short* __restrict__ cb, unsigned* __restrict__ cnt,
    uint2* __restrict__ ent)
{
    const int tid = threadIdx.x, lane = tid & 63;
    const int wu = __builtin_amdgcn_readfirstlane(tid >> 6);   // uniform wave id
    const int p0 = blockIdx.x * 64;

    // ---- fused binning/fill: 576 (p,k) items, fire-and-forget ----
    {
        const int i0 = p0 * KK;
        for (int it = tid; it < 576; it += 256) {
            const int t = i0 + it;
            const float sx = smap[2 * t], sy = smap[2 * t + 1];
            int x0, y0, x1, y1; float dx, dy;
            corners(sx, sy, x0, y0, x1, y1, dx, dy);
            const int g0 = x0 >> 4, g1 = x1 >> 4;   // tile col
            const int t0 = y0 >> 2, t1 = y1 >> 2;   // tile row
            const unsigned w1 = (unsigned)f2h(dx) | ((unsigned)f2h(dy) << 16);
            #define EMIT(ty, gs) { \
                const int bin = (ty) * 32 + (gs); \
                const unsigned lxb = (unsigned)(x0 - (gs) * TW + 1); \
                const unsigned lyb = (unsigned)(y0 - (ty) * TH + 1); \
                const unsigned slot = atomicAdd(&cnt[bin * 16], 1u); \
                if (slot < CAP) ent[(size_t)bin * CAP + slot] = \
                    make_uint2((unsigned)t | (lxb << 20) | (lyb << 25), w1); }
            EMIT(t0, g0);
            if (g1 != g0) EMIT(t0, g1);
            if (t1 != t0) {
                EMIT(t1, g0);
                if (g1 != g0) EMIT(t1, g1);
            }
            #undef EMIT
        }
    }

    // ---- per-lane x fragments (B-operand): 8 ci x 4 px-groups, hi/lo bf16 ----
    const int b = wu >> 1;
    const int obase = (wu & 1) * 16;
    const int colp = lane & 15;          // px column within 16-px group
    const int cig  = (lane >> 4) * 8;    // ci base for this lane's k-chunk
    bf16x8 xh[4], xl[4];
    #pragma unroll
    for (int m = 0; m < 4; ++m) {
        const int p = p0 + m * 16 + colp;
        #pragma unroll
        for (int j = 0; j < 8; ++j) {
            const float v = x[(size_t)(b * 32 + cig + j) * PIX + p];
            const __bf16 h = (__bf16)v;
            xh[m][j] = h;
            xl[m][j] = (__bf16)(v - (float)h);
        }
    }

    const int wo  = ((obase + colp) << 5) + cig;    // o*32 + ci within a k-slab
    const int ch0 = b * 32 + obase + ((lane >> 4) << 2);

    for (int k = 0; k < KK; ++k) {
        const bf16x8 wh = *(const bf16x8*)(wth + k * (COUT * CIN) + wo);
        const bf16x8 wl = *(const bf16x8*)(wtl + k * (COUT * CIN) + wo);
        #pragma unroll
        for (int m = 0; m < 4; ++m) {
            f32x4 a = {0.f, 0.f, 0.f, 0.f};
            a = __builtin_amdgcn_mfma_f32_16x16x32_bf16(wh, xh[m], a, 0, 0, 0);
            a = __builtin_amdgcn_mfma_f32_16x16x32_bf16(wl, xh[m], a, 0, 0, 0);
            a = __builtin_amdgcn_mfma_f32_16x16x32_bf16(wh, xl[m], a, 0, 0, 0);
            const unsigned d0 = (unsigned)f2h(a[0]) | ((unsigned)f2h(a[1]) << 16);
            const unsigned d1 = (unsigned)f2h(a[2]) | ((unsigned)f2h(a[3]) << 16);
            const int px = m * 16 + colp;
            unsigned short* dst = cb + (size_t)(p0 + px) * 576 + k * 64 + ch0;
            *(uint2*)dst = make_uint2(d0, d1);      // 8B store; row merges in L2
        }
    }
}

// ============ pass 2: batched-MFMA gather ====================================
// Per tile (64 px), per 64-entry batch: densify W[px][e] (f16, XOR-swizzled)
// + stage CV[ch][e] from cb; out[px][ch] += W x CV via 16x16x32 f16 MFMA.
// Double-buffered; cb loads issued BEFORE the prev-batch MFMA so their latency
// hides under it; accs in registers; LDS-transposed epilogue.
__global__ __launch_bounds__(256, 4) void k_gather(
    const unsigned short* __restrict__ cb, const uint2* __restrict__ ent,
    const unsigned* __restrict__ cnt, const float* __restrict__ bias,
    float* __restrict__ out)
{
    __shared__ __align__(16) unsigned char smem[32768];
    // W  buf b: smem + b*8192          : f16 [64px][64e], e XOR-swizzled by px&7
    // CV buf b: smem + 16384 + b*8192  : f16 [64ch][64e], e XOR-swizzled by ch&7
    // epilogue: f32 stage[64][65] reuses smem[0..16640)
    const int tid = threadIdx.x, lane = tid & 63;
    const int wv = __builtin_amdgcn_readfirstlane(tid >> 6);   // wave id 0..3
    const int bt = blockIdx.x;
    const int tx0 = (bt & 31) * TW;
    const int ty0 = (bt >> 5) * TH;

    const unsigned count = min(cnt[bt * 16], (unsigned)CAP);
    const uint2* eb = ent + (size_t)bt * CAP;
    const int nb = (int)(count + 63) >> 6;

    f32x4 acc[4] = {{0.f,0.f,0.f,0.f},{0.f,0.f,0.f,0.f},
                    {0.f,0.f,0.f,0.f},{0.f,0.f,0.f,0.f}};

    for (int it = 0; it <= nb; ++it) {
        const int bb = it & 1;
        unsigned short* Wb = (unsigned short*)(smem + bb * 8192);
        unsigned short* Cv = (unsigned short*)(smem + 16384 + bb * 8192);
        if (it < nb) {                              // zero W (8 KB)
            uint4* wq = (uint4*)Wb;
            const uint4 z = make_uint4(0u, 0u, 0u, 0u);
            wq[tid] = z; wq[tid + 256] = z;
        }
        __syncthreads();   // zero visible; prior MFMA done reading buf bb

        unsigned short u[16];
        if (it < nb) {
            // ---- scatter bilinear weights: thread = (entry, corner) ----
            {
                const int eL = tid >> 2, cn = tid & 3;
                const unsigned idx = (unsigned)(it * 64 + eL);
                if (idx < count) {
                    const uint2 r = eb[idx];
                    const int lx = (int)((r.x >> 20) & 31) - 1 + (cn & 1);
                    const int ly = (int)((r.x >> 25) & 7) - 1 + (cn >> 1);
                    if (((unsigned)lx < TW) & ((unsigned)ly < TH)) {
                        const float dx = __half2float(__ushort_as_half((unsigned short)(r.y & 0xFFFF)));
                        const float dy = __half2float(__ushort_as_half((unsigned short)(r.y >> 16)));
                        const float wx = (cn & 1) ? dx : 1.f - dx;
                        const float wy = (cn >> 1) ? dy : 1.f - dy;
                        const int px = ly * TW + lx;
                        Wb[px * 64 + (eL ^ ((px & 7) << 3))] = f2h(wx * wy);
                    }
                }
            }
            // ---- issue CV loads (consumed after the MFMA block below) ----
            #pragma unroll
            for (int j = 0; j < 16; ++j) {
                const unsigned idx = (unsigned)(it * 64 + wv * 16 + j);
                unsigned short v = 0;
                if (idx < count) {
                    const unsigned row = eb[idx].x & 0xFFFFFu;
                    v = cb[((size_t)row << 6) + lane];
                }
                u[j] = v;
            }
        }
        if (it > 0) {
            // ---- MFMA on previous buffer: out[16px x 64ch] += W x CV ----
            const int pb = bb ^ 1;
            const unsigned short* Wp = (const unsigned short*)(smem + pb * 8192);
            const unsigned short* Cp = (const unsigned short*)(smem + 16384 + pb * 8192);
            const int m = lane & 15, kh = lane >> 4;
            const int px = wv * 16 + m;
            f16x8 af[2];
            #pragma unroll
            for (int kc = 0; kc < 2; ++kc)
                af[kc] = *(const f16x8*)(Wp + px * 64 + (((kc * 4 + kh) ^ (px & 7)) << 3));
            #pragma unroll
            for (int n = 0; n < 4; ++n) {
                const int ch = n * 16 + m;
                #pragma unroll
                for (int kc = 0; kc < 2; ++kc) {
                    const f16x8 bf = *(const f16x8*)(Cp + ch * 64 + (((kc * 4 + kh) ^ (ch & 7)) << 3));
                    acc[n] = __builtin_amdgcn_mfma_f32_16x16x32_f16(af[kc], bf, acc[n], 0, 0, 0);
                }
            }
        }
        if (it < nb) {
            // ---- pack staged CV rows into LDS (waits on the u[] loads) ----
            uint4* cvq = (uint4*)Cv;
            const uint4 pk0 = make_uint4(
                (unsigned)u[0]  | ((unsigned)u[1]  << 16),
                (unsigned)u[2]  | ((unsigned)u[3]  << 16),
                (unsigned)u[4]  | ((unsigned)u[5]  << 16),
                (unsigned)u[6]  | ((unsigned)u[7]  << 16));
            const uint4 pk1 = make_uint4(
                (unsigned)u[8]  | ((unsigned)u[9]  << 16),
                (unsigned)u[10] | ((unsigned)u[11] << 16),
                (unsigned)u[12] | ((unsigned)u[13] << 16),
                (unsigned)u[14] | ((unsigned)u[15] << 16));
            cvq[lane * 8 + ((wv * 2)     ^ (lane & 7))] = pk0;
            cvq[lane * 8 + ((wv * 2 + 1) ^ (lane & 7))] = pk1;
        }
        __syncthreads();   // build of buf bb complete; MFMA of bb^1 done
    }

    // ---- epilogue: transpose through LDS, coalesced store ----
    float* stage = (float*)smem;
    #pragma unroll
    for (int n = 0; n < 4; ++n) {
        #pragma unroll
        for (int r = 0; r < 4; ++r)
            stage[(wv * 16 + (lane >> 4) * 4 + r) * 65 + n * 16 + (lane & 15)] = acc[n][r];
    }
    __syncthreads();
    const int py = lane >> 4, pxx = lane & 15;
    const size_t q = (size_t)(ty0 + py) * OW + tx0 + pxx;
    #pragma unroll
    for (int j = 0; j < 16; ++j) {
        const int c = wv * 16 + j;
        out[(size_t)c * OHOW + q] = stage[(py * 16 + pxx) * 65 + c] + bias[c & 31];
    }
}

// ================= fallback (no ws requirement) ==============================
__global__ __launch_bounds__(576) void mtc_scatter_direct(
    const float* __restrict__ x, const float* __restrict__ weight,
    const float* __restrict__ smap, float* __restrict__ acc)
{
    __shared__ float xs[64][68];
    __shared__ float sm[64 * KK * 2];
    const int t = threadIdx.x;
    const int p0 = blockIdx.x * 64;
    if (t < 512) {
        const int pp = t & 63, c0 = t >> 6;
        #pragma unroll
        for (int ch = 0; ch < 8; ++ch) {
            const int c = c0 + ch * 8;
            xs[pp][c] = x[(size_t)c * PIX + p0 + pp];
        }
    }
    for (int i = t; i < 64 * KK * 2; i += 576)
        sm[i] = smap[(size_t)p0 * (KK * 2) + i];
    const int k = t >> 6, lane = t & 63, b = lane >> 5, o = lane & 31;
    float wreg[CIN];
    #pragma unroll
    for (int i = 0; i < CIN; ++i) wreg[i] = weight[(i * COUT + o) * KK + k];
    __syncthreads();
    for (int pp = 0; pp < 64; ++pp) {
        const float sx = sm[(pp * KK + k) * 2], sy = sm[(pp * KK + k) * 2 + 1];
        int x0, y0, x1, y1; float dx, dy;
        corners(sx, sy, x0, y0, x1, y1, dx, dy);
        const float* xrow = &xs[pp][b * 32];
        float cv = 0.f;
        #pragma unroll
        for (int j = 0; j < 8; ++j) {
            const float4 xv = *(const float4*)(xrow + 4 * j);
            cv += xv.x * wreg[4*j] + xv.y * wreg[4*j+1] + xv.z * wreg[4*j+2] + xv.w * wreg[4*j+3];
        }
        const size_t base = (size_t)lane * OHOW;
        atomicAdd(&acc[base + y0 * OW + x0], cv * (1.f - dx) * (1.f - dy));
        atomicAdd(&acc[base + y0 * OW + x1], cv * dx * (1.f - dy));
        atomicAdd(&acc[base + y1 * OW + x0], cv * (1.f - dx) * dy);
        atomicAdd(&acc[base + y1 * OW + x1], cv * dx * dy);
    }
}

__global__ __launch_bounds__(256) void mtc_bias_add(
    float* __restrict__ out, const float* __restrict__ bias)
{
    const size_t i = (size_t)blockIdx.x * 256 + threadIdx.x;
    out[i] += bias[(i >> 18) & 31];
}

extern "C" void kernel_launch(void* const* d_in, const int* in_sizes, int n_in,
                              void* d_out, int out_size, void* d_ws, size_t ws_size,
                              hipStream_t stream) {
    const float* x      = (const float*)d_in[0];
    const float* weight = (const float*)d_in[1];
    const float* bias   = (const float*)d_in[2];
    const float* smap   = (const float*)d_in[3];
    float* out = (float*)d_out;
    char* ws = (char*)d_ws;

    if (ws_size >= WS_NEED) {
        unsigned* cnt = (unsigned*)(ws + OFF_CNT);
        __bf16* wth   = (__bf16*)(ws + OFF_WT);
        __bf16* wtl   = wth + KK * COUT * CIN;
        uint2* ent    = (uint2*)(ws + OFF_ENT);
        unsigned short* cb = (unsigned short*)(ws + OFF_CB);

        hipMemsetAsync(cnt, 0, NBIN * 16 * sizeof(unsigned), stream);
        k_wtb<<<(KK * COUT * CIN + 255) / 256, 256, 0, stream>>>(weight, wth, wtl);
        k_contrib3<<<PIX / 64, 256, 0, stream>>>(x, wth, wtl, smap, cb, cnt, ent);
        k_gather<<<NTILE, 256, 0, stream>>>(cb, ent, cnt, bias, out);
    } else {
        hipMemsetAsync(out, 0, (size_t)OHOW * NCH * sizeof(float), stream);
        mtc_scatter_direct<<<PIX / 64, 576, 0, stream>>>(x, weight, smap, out);
        mtc_bias_add<<<(OHOW * NCH) / 256, 256, 0, stream>>>(out, bias);
    }
}

// Round 4
// 183.308 us; speedup vs baseline: 1.4626x; 1.1916x over previous
//
#include <hip/hip_runtime.h>
#include <hip/hip_fp16.h>

#define CIN 32
#define COUT 32
#define KK 9
#define PIX 65536          // 256*256 input pixels
#define OH 512
#define OW 512
#define OHOW (OH*OW)
#define NCH 64             // B*COUT
#define TW 16              // tile width  (x)
#define TH 4               // tile height (y)
#define TPX (TW*TH)        // 64 px per tile
#define NTX (OW/TW)        // 32
#define NTY (OH/TH)        // 128
#define NTILE (NTX*NTY)    // 4096
#define NBIN NTILE         // per-tile bins
#define NPK (PIX*KK)       // 589824 (p,k) pairs
#define CAP 384            // fixed bin capacity; lambda=191, P(overflow)~1e-40

// ---- ws layout (bytes) ----
#define OFF_CNT 0                              // u32[NBIN*16] 256 KB (64B-padded counters)
#define OFF_WT  (256*1024)                     // bf16 hi[9216] + lo[9216] = 36.9 KB
#define OFF_ENT (512*1024)                     // uint2[NBIN*CAP]  12.6 MB
#define OFF_CB  (OFF_ENT + (size_t)NBIN*CAP*8) // f16[NPK*64] 75.5 MB
#define WS_NEED (OFF_CB + (size_t)NPK*NCH*2)   // ~88.6 MB

typedef __bf16    bf16x8 __attribute__((ext_vector_type(8)));
typedef _Float16  f16x8  __attribute__((ext_vector_type(8)));
typedef float     f32x4  __attribute__((ext_vector_type(4)));

__device__ __forceinline__ unsigned short f2h(float v)
{
    return __half_as_ushort(__float2half_rn(v));
}

// corner setup (clips never fire for this input; kept for safety)
__device__ __forceinline__ void corners(float sx, float sy,
    int& x0, int& y0, int& x1, int& y1, float& dx, float& dy)
{
    const float x0f = floorf(sx), y0f = floorf(sy);
    dx = sx - x0f; dy = sy - y0f;
    x0 = min(max((int)x0f, 0), OW - 1);
    y0 = min(max((int)y0f, 0), OH - 1);
    x1 = min(x0 + 1, OW - 1);
    y1 = min(y0 + 1, OH - 1);
}

// ============ pass 0: W[i][o][k] -> bf16 hi/lo [k][o][i] =====================
__global__ __launch_bounds__(256) void k_wtb(
    const float* __restrict__ w, __bf16* __restrict__ wth, __bf16* __restrict__ wtl)
{
    const int t = blockIdx.x * 256 + threadIdx.x;   // (k*32+o)*32 + i
    if (t < KK * COUT * CIN) {
        const int i = t & 31;
        const int o = (t >> 5) & 31;
        const int k = t >> 10;
        const float v = w[(i * COUT + o) * KK + k];
        const __bf16 h = (__bf16)v;
        wth[t] = h;
        wtl[t] = (__bf16)(v - (float)h);
    }
}

// ============ pass 1: contrib via MFMA + deferred binning, zero barriers =====
// Wave wu owns px [wu*16, wu*16+16), ALL 64 channels (A-frag W is b-independent
// so MFMA count is unchanged). Per k: 4 ch-groups x 3 hi/lo MFMAs; D-frags
// staged in a per-wave private LDS patch (double-buffered by k&1, lgkmcnt-only
// sync), flushed as 4x16B-lane contiguous 64B segments -> full-sector stores.
// Binning: all atomics fired up-front into statically-indexed regs; the
// dependent ent[] stores are deferred to AFTER the k-loop so the ~700cy
// device-scope atomic round trips hide under the whole MFMA phase.
__global__ __launch_bounds__(256, 1) void k_contrib4(
    const float* __restrict__ x, const __bf16* __restrict__ wth,
    const __bf16* __restrict__ wtl, const float* __restrict__ smap,
    unsigned short* __restrict__ cb, unsigned* __restrict__ cnt,
    uint2* __restrict__ ent)
{
    __shared__ __align__(16) unsigned short patch[4][2][16][72]; // 18.4 KB
    const int tid = threadIdx.x, lane = tid & 63;
    const int wu = __builtin_amdgcn_readfirstlane(tid >> 6);   // uniform wave id
    const int p0 = blockIdx.x * 64;
    const int colp = lane & 15;          // px within wave / o within 16 / B-col
    const int q    = lane >> 4;          // k-chunk quad
    const int cig  = q * 8;              // ci base for MFMA fragments

    // ---- phase A: compute emits + fire atomics (returns consumed at the end)
    unsigned aS[3][4], aA[3][4], aR[3][4], aW[3];
    #pragma unroll
    for (int it = 0; it < 3; ++it) {
        const int idx = tid + it * 256;
        const bool vit = idx < 576;
        const int t = min(p0 * KK + idx, NPK - 1);
        const float sx = smap[2 * t], sy = smap[2 * t + 1];
        int x0, y0, x1, y1; float dx, dy;
        corners(sx, sy, x0, y0, x1, y1, dx, dy);
        const int g0 = x0 >> 4, g1 = x1 >> 4;   // tile col
        const int t0 = y0 >> 2, t1 = y1 >> 2;   // tile row
        aW[it] = (unsigned)f2h(dx) | ((unsigned)f2h(dy) << 16);
        const bool dg = (g1 != g0), dt = (t1 != t0);
        const bool cond[4] = { vit, vit && dg, vit && dt, vit && dg && dt };
        const int  tys[4]  = { t0, t0, t1, t1 };
        const int  gss[4]  = { g0, g1, g0, g1 };
        #pragma unroll
        for (int e = 0; e < 4; ++e) {
            unsigned slot = 0xFFFFFFFFu;
            const int bin = tys[e] * 32 + gss[e];
            const unsigned lxb = (unsigned)(x0 - gss[e] * TW + 1);
            const unsigned lyb = (unsigned)(y0 - tys[e] * TH + 1);
            if (cond[e]) slot = atomicAdd(&cnt[bin * 16], 1u);
            aS[it][e] = slot;
            aA[it][e] = (unsigned)bin * CAP;
            aR[it][e] = (unsigned)t | (lxb << 20) | (lyb << 25);
        }
    }

    // ---- phase B: x fragments for this wave's 16 px, BOTH b halves ----
    bf16x8 xh[2], xl[2];
    #pragma unroll
    for (int b = 0; b < 2; ++b) {
        const int p = p0 + wu * 16 + colp;
        #pragma unroll
        for (int j = 0; j < 8; ++j) {
            const float v = x[(size_t)(b * 32 + cig + j) * PIX + p];
            const __bf16 h = (__bf16)v;
            xh[b][j] = h;
            xl[b][j] = (__bf16)(v - (float)h);
        }
    }

    // ---- phase C: k-loop, MFMA -> per-wave LDS patch -> full-sector stores --
    const int pxr = lane >> 2, cc = lane & 3;   // flush mapping
    for (int k = 0; k < KK; ++k) {
        const int kb = k & 1;
        const __bf16* wb = wth + k * (COUT * CIN);
        const __bf16* lb = wtl + k * (COUT * CIN);
        bf16x8 wh[2], wl[2];
        #pragma unroll
        for (int oh = 0; oh < 2; ++oh) {
            wh[oh] = *(const bf16x8*)(wb + (oh * 16 + colp) * 32 + cig);
            wl[oh] = *(const bf16x8*)(lb + (oh * 16 + colp) * 32 + cig);
        }
        #pragma unroll
        for (int cg = 0; cg < 4; ++cg) {        // ch group: b=cg>>1, oh=cg&1
            const int b = cg >> 1, oh = cg & 1;
            f32x4 a = {0.f, 0.f, 0.f, 0.f};
            a = __builtin_amdgcn_mfma_f32_16x16x32_bf16(wh[oh], xh[b], a, 0, 0, 0);
            a = __builtin_amdgcn_mfma_f32_16x16x32_bf16(wl[oh], xh[b], a, 0, 0, 0);
            a = __builtin_amdgcn_mfma_f32_16x16x32_bf16(wh[oh], xl[b], a, 0, 0, 0);
            const unsigned d0 = (unsigned)f2h(a[0]) | ((unsigned)f2h(a[1]) << 16);
            const unsigned d1 = (unsigned)f2h(a[2]) | ((unsigned)f2h(a[3]) << 16);
            // px=colp, ch = cg*16 + q*4  (identical channel map to round-3)
            *(uint2*)&patch[wu][kb][colp][cg * 16 + q * 4] = make_uint2(d0, d1);
        }
        // per-wave flush: lane (pxr, cc) -> 16B at row pxr, bytes [cc*16, +64+cc*16)
        const uint4 a0 = *(const uint4*)&patch[wu][kb][pxr][cc * 8];
        const uint4 a1 = *(const uint4*)&patch[wu][kb][pxr][32 + cc * 8];
        unsigned short* dst = cb + (size_t)(p0 + wu * 16 + pxr) * 576 + k * 64 + cc * 8;
        *(uint4*)dst        = a0;               // 4 lanes = 64B contiguous sector
        *(uint4*)(dst + 32) = a1;
    }

    // ---- phase D: deferred ent stores (atomic returns now long-arrived) ----
    #pragma unroll
    for (int it = 0; it < 3; ++it) {
        #pragma unroll
        for (int e = 0; e < 4; ++e) {
            if (aS[it][e] < CAP)
                ent[(size_t)aA[it][e] + aS[it][e]] = make_uint2(aR[it][e], aW[it]);
        }
    }
}

// ============ pass 2: batched-MFMA gather (unchanged from round 3) ===========
__global__ __launch_bounds__(256, 4) void k_gather(
    const unsigned short* __restrict__ cb, const uint2* __restrict__ ent,
    const unsigned* __restrict__ cnt, const float* __restrict__ bias,
    float* __restrict__ out)
{
    __shared__ __align__(16) unsigned char smem[32768];
    // W  buf b: smem + b*8192          : f16 [64px][64e], e XOR-swizzled by px&7
    // CV buf b: smem + 16384 + b*8192  : f16 [64ch][64e], e XOR-swizzled by ch&7
    // epilogue: f32 stage[64][65] reuses smem[0..16640)
    const int tid = threadIdx.x, lane = tid & 63;
    const int wv = __builtin_amdgcn_readfirstlane(tid >> 6);   // wave id 0..3
    const int bt = blockIdx.x;
    const int tx0 = (bt & 31) * TW;
    const int ty0 = (bt >> 5) * TH;

    const unsigned count = min(cnt[bt * 16], (unsigned)CAP);
    const uint2* eb = ent + (size_t)bt * CAP;
    const int nb = (int)(count + 63) >> 6;

    f32x4 acc[4] = {{0.f,0.f,0.f,0.f},{0.f,0.f,0.f,0.f},
                    {0.f,0.f,0.f,0.f},{0.f,0.f,0.f,0.f}};

    for (int it = 0; it <= nb; ++it) {
        const int bb = it & 1;
        unsigned short* Wb = (unsigned short*)(smem + bb * 8192);
        unsigned short* Cv = (unsigned short*)(smem + 16384 + bb * 8192);
        if (it < nb) {                              // zero W (8 KB)
            uint4* wq = (uint4*)Wb;
            const uint4 z = make_uint4(0u, 0u, 0u, 0u);
            wq[tid] = z; wq[tid + 256] = z;
        }
        __syncthreads();   // zero visible; prior MFMA done reading buf bb

        unsigned short u[16];
        if (it < nb) {
            // ---- scatter bilinear weights: thread = (entry, corner) ----
            {
                const int eL = tid >> 2, cn = tid & 3;
                const unsigned idx = (unsigned)(it * 64 + eL);
                if (idx < count) {
                    const uint2 r = eb[idx];
                    const int lx = (int)((r.x >> 20) & 31) - 1 + (cn & 1);
                    const int ly = (int)((r.x >> 25) & 7) - 1 + (cn >> 1);
                    if (((unsigned)lx < TW) & ((unsigned)ly < TH)) {
                        const float dx = __half2float(__ushort_as_half((unsigned short)(r.y & 0xFFFF)));
                        const float dy = __half2float(__ushort_as_half((unsigned short)(r.y >> 16)));
                        const float wx = (cn & 1) ? dx : 1.f - dx;
                        const float wy = (cn >> 1) ? dy : 1.f - dy;
                        const int px = ly * TW + lx;
                        Wb[px * 64 + (eL ^ ((px & 7) << 3))] = f2h(wx * wy);
                    }
                }
            }
            // ---- issue CV loads (consumed after the MFMA block below) ----
            #pragma unroll
            for (int j = 0; j < 16; ++j) {
                const unsigned idx = (unsigned)(it * 64 + wv * 16 + j);
                unsigned short v = 0;
                if (idx < count) {
                    const unsigned row = eb[idx].x & 0xFFFFFu;
                    v = cb[((size_t)row << 6) + lane];
                }
                u[j] = v;
            }
        }
        if (it > 0) {
            // ---- MFMA on previous buffer: out[16px x 64ch] += W x CV ----
            const int pb = bb ^ 1;
            const unsigned short* Wp = (const unsigned short*)(smem + pb * 8192);
            const unsigned short* Cp = (const unsigned short*)(smem + 16384 + pb * 8192);
            const int m = lane & 15, kh = lane >> 4;
            const int px = wv * 16 + m;
            f16x8 af[2];
            #pragma unroll
            for (int kc = 0; kc < 2; ++kc)
                af[kc] = *(const f16x8*)(Wp + px * 64 + (((kc * 4 + kh) ^ (px & 7)) << 3));
            #pragma unroll
            for (int n = 0; n < 4; ++n) {
                const int ch = n * 16 + m;
                #pragma unroll
                for (int kc = 0; kc < 2; ++kc) {
                    const f16x8 bf = *(const f16x8*)(Cp + ch * 64 + (((kc * 4 + kh) ^ (ch & 7)) << 3));
                    acc[n] = __builtin_amdgcn_mfma_f32_16x16x32_f16(af[kc], bf, acc[n], 0, 0, 0);
                }
            }
        }
        if (it < nb) {
            // ---- pack staged CV rows into LDS (waits on the u[] loads) ----
            uint4* cvq = (uint4*)Cv;
            const uint4 pk0 = make_uint4(
                (unsigned)u[0]  | ((unsigned)u[1]  << 16),
                (unsigned)u[2]  | ((unsigned)u[3]  << 16),
                (unsigned)u[4]  | ((unsigned)u[5]  << 16),
                (unsigned)u[6]  | ((unsigned)u[7]  << 16));
            const uint4 pk1 = make_uint4(
                (unsigned)u[8]  | ((unsigned)u[9]  << 16),
                (unsigned)u[10] | ((unsigned)u[11] << 16),
                (unsigned)u[12] | ((unsigned)u[13] << 16),
                (unsigned)u[14] | ((unsigned)u[15] << 16));
            cvq[lane * 8 + ((wv * 2)     ^ (lane & 7))] = pk0;
            cvq[lane * 8 + ((wv * 2 + 1) ^ (lane & 7))] = pk1;
        }
        __syncthreads();   // build of buf bb complete; MFMA of bb^1 done
    }

    // ---- epilogue: transpose through LDS, coalesced store ----
    float* stage = (float*)smem;
    #pragma unroll
    for (int n = 0; n < 4; ++n) {
        #pragma unroll
        for (int r = 0; r < 4; ++r)
            stage[(wv * 16 + (lane >> 4) * 4 + r) * 65 + n * 16 + (lane & 15)] = acc[n][r];
    }
    __syncthreads();
    const int py = lane >> 4, pxx = lane & 15;
    const size_t q = (size_t)(ty0 + py) * OW + tx0 + pxx;
    #pragma unroll
    for (int j = 0; j < 16; ++j) {
        const int c = wv * 16 + j;
        out[(size_t)c * OHOW + q] = stage[(py * 16 + pxx) * 65 + c] + bias[c & 31];
    }
}

// ================= fallback (no ws requirement) ==============================
__global__ __launch_bounds__(576) void mtc_scatter_direct(
    const float* __restrict__ x, const float* __restrict__ weight,
    const float* __restrict__ smap, float* __restrict__ acc)
{
    __shared__ float xs[64][68];
    __shared__ float sm[64 * KK * 2];
    const int t = threadIdx.x;
    const int p0 = blockIdx.x * 64;
    if (t < 512) {
        const int pp = t & 63, c0 = t >> 6;
        #pragma unroll
        for (int ch = 0; ch < 8; ++ch) {
            const int c = c0 + ch * 8;
            xs[pp][c] = x[(size_t)c * PIX + p0 + pp];
        }
    }
    for (int i = t; i < 64 * KK * 2; i += 576)
        sm[i] = smap[(size_t)p0 * (KK * 2) + i];
    const int k = t >> 6, lane = t & 63, b = lane >> 5, o = lane & 31;
    float wreg[CIN];
    #pragma unroll
    for (int i = 0; i < CIN; ++i) wreg[i] = weight[(i * COUT + o) * KK + k];
    __syncthreads();
    for (int pp = 0; pp < 64; ++pp) {
        const float sx = sm[(pp * KK + k) * 2], sy = sm[(pp * KK + k) * 2 + 1];
        int x0, y0, x1, y1; float dx, dy;
        corners(sx, sy, x0, y0, x1, y1, dx, dy);
        const float* xrow = &xs[pp][b * 32];
        float cv = 0.f;
        #pragma unroll
        for (int j = 0; j < 8; ++j) {
            const float4 xv = *(const float4*)(xrow + 4 * j);
            cv += xv.x * wreg[4*j] + xv.y * wreg[4*j+1] + xv.z * wreg[4*j+2] + xv.w * wreg[4*j+3];
        }
        const size_t base = (size_t)lane * OHOW;
        atomicAdd(&acc[base + y0 * OW + x0], cv * (1.f - dx) * (1.f - dy));
        atomicAdd(&acc[base + y0 * OW + x1], cv * dx * (1.f - dy));
        atomicAdd(&acc[base + y1 * OW + x0], cv * (1.f - dx) * dy);
        atomicAdd(&acc[base + y1 * OW + x1], cv * dx * dy);
    }
}

__global__ __launch_bounds__(256) void mtc_bias_add(
    float* __restrict__ out, const float* __restrict__ bias)
{
    const size_t i = (size_t)blockIdx.x * 256 + threadIdx.x;
    out[i] += bias[(i >> 18) & 31];
}

extern "C" void kernel_launch(void* const* d_in, const int* in_sizes, int n_in,
                              void* d_out, int out_size, void* d_ws, size_t ws_size,
                              hipStream_t stream) {
    const float* x      = (const float*)d_in[0];
    const float* weight = (const float*)d_in[1];
    const float* bias   = (const float*)d_in[2];
    const float* smap   = (const float*)d_in[3];
    float* out = (float*)d_out;
    char* ws = (char*)d_ws;

    if (ws_size >= WS_NEED) {
        unsigned* cnt = (unsigned*)(ws + OFF_CNT);
        __bf16* wth   = (__bf16*)(ws + OFF_WT);
        __bf16* wtl   = wth + KK * COUT * CIN;
        uint2* ent    = (uint2*)(ws + OFF_ENT);
        unsigned short* cb = (unsigned short*)(ws + OFF_CB);

        hipMemsetAsync(cnt, 0, NBIN * 16 * sizeof(unsigned), stream);
        k_wtb<<<(KK * COUT * CIN + 255) / 256, 256, 0, stream>>>(weight, wth, wtl);
        k_contrib4<<<PIX / 64, 256, 0, stream>>>(x, wth, wtl, smap, cb, cnt, ent);
        k_gather<<<NTILE, 256, 0, stream>>>(cb, ent, cnt, bias, out);
    } else {
        hipMemsetAsync(out, 0, (size_t)OHOW * NCH * sizeof(float), stream);
        mtc_scatter_direct<<<PIX / 64, 576, 0, stream>>>(x, weight, smap, out);
        mtc_bias_add<<<(OHOW * NCH) / 256, 256, 0, stream>>>(out, bias);
    }
}

// Round 5
// 169.543 us; speedup vs baseline: 1.5814x; 1.0812x over previous
//
#include <hip/hip_runtime.h>
#include <hip/hip_fp16.h>

#define CIN 32
#define COUT 32
#define KK 9
#define PIX 65536          // 256*256 input pixels
#define OH 512
#define OW 512
#define OHOW (OH*OW)
#define NCH 64             // B*COUT
#define TW 16              // tile width  (x)
#define TH 4               // tile height (y)
#define TPX (TW*TH)        // 64 px per tile
#define NTX (OW/TW)        // 32
#define NTY (OH/TH)        // 128
#define NTILE (NTX*NTY)    // 4096
#define NBIN NTILE         // per-tile bins
#define NPK (PIX*KK)       // 589824 (p,k) pairs
#define NSEG 4             // bins segmented by source blockIdx&3 (~XCD pairs)
#define SCAP 96            // per-(bin,seg) capacity; lambda~48, P(ovfl)~1e-4 grid-wide
#define CAPT (NSEG*SCAP)   // 384 entries per tile max

// ---- ws layout (bytes) ----
#define OFF_CNT 0                              // u32[NSEG][NBIN] 64 KB (seg-major)
#define OFF_WT  (256*1024)                     // bf16 hi[9216] + lo[9216] = 36.9 KB
#define OFF_ENT (512*1024)                     // uint2[NBIN*NSEG*SCAP]  12.6 MB
#define OFF_CB  (OFF_ENT + (size_t)NBIN*NSEG*SCAP*8) // f16[NPK*64] 75.5 MB
#define WS_NEED (OFF_CB + (size_t)NPK*NCH*2)   // ~88.6 MB

typedef __bf16    bf16x8 __attribute__((ext_vector_type(8)));
typedef _Float16  f16x8  __attribute__((ext_vector_type(8)));
typedef float     f32x4  __attribute__((ext_vector_type(4)));

__device__ __forceinline__ unsigned short f2h(float v)
{
    return __half_as_ushort(__float2half_rn(v));
}

// corner setup (clips never fire for this input; kept for safety)
__device__ __forceinline__ void corners(float sx, float sy,
    int& x0, int& y0, int& x1, int& y1, float& dx, float& dy)
{
    const float x0f = floorf(sx), y0f = floorf(sy);
    dx = sx - x0f; dy = sy - y0f;
    x0 = min(max((int)x0f, 0), OW - 1);
    y0 = min(max((int)y0f, 0), OH - 1);
    x1 = min(x0 + 1, OW - 1);
    y1 = min(y0 + 1, OH - 1);
}

// ============ pass 0: W[i][o][k] -> bf16 hi/lo [k][o][i] =====================
__global__ __launch_bounds__(256) void k_wtb(
    const float* __restrict__ w, __bf16* __restrict__ wth, __bf16* __restrict__ wtl)
{
    const int t = blockIdx.x * 256 + threadIdx.x;   // (k*32+o)*32 + i
    if (t < KK * COUT * CIN) {
        const int i = t & 31;
        const int o = (t >> 5) & 31;
        const int k = t >> 10;
        const float v = w[(i * COUT + o) * KK + k];
        const __bf16 h = (__bf16)v;
        wth[t] = h;
        wtl[t] = (__bf16)(v - (float)h);
    }
}

// ============ pass 1: contrib via MFMA + seg-local deferred binning ==========
// Issue order is the point: x fragments and W(k=0) are issued BEFORE the
// binning atomics, and W(k+1) is prefetched inside the k-loop. vmcnt is
// in-order, so no compute wait ever sits behind an atomic; only the final
// deferred ent stores consume slot returns. Atomics go to seg=blockIdx&3
// counter regions (each touched by ~2 XCDs) to cut cross-XCD line bouncing.
__global__ __launch_bounds__(256, 1) void k_contrib5(
    const float* __restrict__ x, const __bf16* __restrict__ wth,
    const __bf16* __restrict__ wtl, const float* __restrict__ smap,
    unsigned short* __restrict__ cb, unsigned* __restrict__ cnt,
    uint2* __restrict__ ent)
{
    __shared__ __align__(16) unsigned short patch[4][2][16][72]; // 18.4 KB
    const int tid = threadIdx.x, lane = tid & 63;
    const int wu = __builtin_amdgcn_readfirstlane(tid >> 6);   // uniform wave id
    const int p0 = blockIdx.x * 64;
    const unsigned seg = blockIdx.x & 3;
    const int colp = lane & 15;          // px within wave / o within 16 / B-col
    const int q    = lane >> 4;          // k-chunk quad
    const int cig  = q * 8;              // ci base for MFMA fragments

    // ---- phase B: x fragments for this wave's 16 px, BOTH b halves ----
    bf16x8 xh[2], xl[2];
    #pragma unroll
    for (int b = 0; b < 2; ++b) {
        const int p = p0 + wu * 16 + colp;
        #pragma unroll
        for (int j = 0; j < 8; ++j) {
            const float v = x[(size_t)(b * 32 + cig + j) * PIX + p];
            const __bf16 h = (__bf16)v;
            xh[b][j] = h;
            xl[b][j] = (__bf16)(v - (float)h);
        }
    }
    // ---- W(k=0) prefetch (also ahead of the atomics) ----
    bf16x8 wwh[2][2], wwl[2][2];         // [buf][oh]
    #pragma unroll
    for (int oh = 0; oh < 2; ++oh) {
        wwh[0][oh] = *(const bf16x8*)(wth + (oh * 16 + colp) * 32 + cig);
        wwl[0][oh] = *(const bf16x8*)(wtl + (oh * 16 + colp) * 32 + cig);
    }

    // ---- phase A: binning; atomics fired LAST, returns consumed at the end --
    unsigned aS[3][4], aA[3][4], aR[3][4], aW[3];
    #pragma unroll
    for (int it = 0; it < 3; ++it) {
        const int idx = tid + it * 256;
        const bool vit = idx < 576;
        const int t = min(p0 * KK + idx, NPK - 1);
        const float sx = smap[2 * t], sy = smap[2 * t + 1];
        int x0, y0, x1, y1; float dx, dy;
        corners(sx, sy, x0, y0, x1, y1, dx, dy);
        const int g0 = x0 >> 4, g1 = x1 >> 4;   // tile col
        const int t0 = y0 >> 2, t1 = y1 >> 2;   // tile row
        aW[it] = (unsigned)f2h(dx) | ((unsigned)f2h(dy) << 16);
        const bool dg = (g1 != g0), dt = (t1 != t0);
        const bool cond[4] = { vit, vit && dg, vit && dt, vit && dg && dt };
        const int  tys[4]  = { t0, t0, t1, t1 };
        const int  gss[4]  = { g0, g1, g0, g1 };
        #pragma unroll
        for (int e = 0; e < 4; ++e) {
            unsigned slot = 0xFFFFFFFFu;
            const int bin = tys[e] * 32 + gss[e];
            const unsigned lxb = (unsigned)(x0 - gss[e] * TW + 1);
            const unsigned lyb = (unsigned)(y0 - tys[e] * TH + 1);
            if (cond[e]) slot = atomicAdd(&cnt[seg * NBIN + bin], 1u);
            aS[it][e] = slot;
            aA[it][e] = ((unsigned)bin * NSEG + seg) * SCAP;
            aR[it][e] = (unsigned)t | (lxb << 20) | (lyb << 25);
        }
    }

    // ---- phase C: k-loop, MFMA -> per-wave LDS patch -> full-sector stores --
    const int pxr = lane >> 2, cc = lane & 3;   // flush mapping
    #pragma unroll
    for (int k = 0; k < KK; ++k) {
        const int kb = k & 1;
        const int cur = k & 1, nxt = cur ^ 1;
        if (k + 1 < KK) {                       // prefetch W(k+1)
            const __bf16* wb = wth + (k + 1) * (COUT * CIN);
            const __bf16* lb = wtl + (k + 1) * (COUT * CIN);
            #pragma unroll
            for (int oh = 0; oh < 2; ++oh) {
                wwh[nxt][oh] = *(const bf16x8*)(wb + (oh * 16 + colp) * 32 + cig);
                wwl[nxt][oh] = *(const bf16x8*)(lb + (oh * 16 + colp) * 32 + cig);
            }
        }
        #pragma unroll
        for (int cg = 0; cg < 4; ++cg) {        // ch group: b=cg>>1, oh=cg&1
            const int b = cg >> 1, oh = cg & 1;
            f32x4 a = {0.f, 0.f, 0.f, 0.f};
            a = __builtin_amdgcn_mfma_f32_16x16x32_bf16(wwh[cur][oh], xh[b], a, 0, 0, 0);
            a = __builtin_amdgcn_mfma_f32_16x16x32_bf16(wwl[cur][oh], xh[b], a, 0, 0, 0);
            a = __builtin_amdgcn_mfma_f32_16x16x32_bf16(wwh[cur][oh], xl[b], a, 0, 0, 0);
            const unsigned d0 = (unsigned)f2h(a[0]) | ((unsigned)f2h(a[1]) << 16);
            const unsigned d1 = (unsigned)f2h(a[2]) | ((unsigned)f2h(a[3]) << 16);
            // px=colp, ch = cg*16 + q*4
            *(uint2*)&patch[wu][kb][colp][cg * 16 + q * 4] = make_uint2(d0, d1);
        }
        // per-wave flush: lane (pxr, cc) -> 16B each, 4 lanes = 64B sector
        const uint4 a0 = *(const uint4*)&patch[wu][kb][pxr][cc * 8];
        const uint4 a1 = *(const uint4*)&patch[wu][kb][pxr][32 + cc * 8];
        unsigned short* dst = cb + (size_t)(p0 + wu * 16 + pxr) * 576 + k * 64 + cc * 8;
        *(uint4*)dst        = a0;
        *(uint4*)(dst + 32) = a1;
    }

    // ---- phase D: deferred ent stores (atomic returns long-arrived) ----
    #pragma unroll
    for (int it = 0; it < 3; ++it) {
        #pragma unroll
        for (int e = 0; e < 4; ++e) {
            if (aS[it][e] < SCAP)
                ent[(size_t)aA[it][e] + aS[it][e]] = make_uint2(aR[it][e], aW[it]);
        }
    }
}

// ============ pass 2: batched-MFMA gather with LDS entry list ================
// Per tile: merge the 4 segment lists into a contiguous LDS list (<=384),
// then per 64-entry batch: densify W[px][e] (f16, XOR-swizzled) + stage
// CV[ch][e] from cb; out[px][ch] += W x CV via 16x16x32 f16 MFMA.
__global__ __launch_bounds__(256, 4) void k_gather(
    const unsigned short* __restrict__ cb, const uint2* __restrict__ ent,
    const unsigned* __restrict__ cnt, const float* __restrict__ bias,
    float* __restrict__ out)
{
    __shared__ __align__(16) unsigned char smem[32768];
    __shared__ __align__(16) uint2 elist[CAPT];     // 3 KB merged entry list
    // W  buf b: smem + b*8192          : f16 [64px][64e], e XOR-swizzled by px&7
    // CV buf b: smem + 16384 + b*8192  : f16 [64ch][64e], e XOR-swizzled by ch&7
    // epilogue: f32 stage[64][65] reuses smem[0..16640)
    const int tid = threadIdx.x, lane = tid & 63;
    const int wv = __builtin_amdgcn_readfirstlane(tid >> 6);   // wave id 0..3
    const int bt = blockIdx.x;
    const int tx0 = (bt & 31) * TW;
    const int ty0 = (bt >> 5) * TH;

    // ---- merge segment lists into LDS ----
    const unsigned c0 = min(cnt[0 * NBIN + bt], (unsigned)SCAP);
    const unsigned c1 = min(cnt[1 * NBIN + bt], (unsigned)SCAP);
    const unsigned c2 = min(cnt[2 * NBIN + bt], (unsigned)SCAP);
    const unsigned c3 = min(cnt[3 * NBIN + bt], (unsigned)SCAP);
    const unsigned o1 = c0, o2 = c0 + c1, o3 = o2 + c2;
    const unsigned count = o3 + c3;
    {
        const uint2* e0 = ent + ((size_t)bt * NSEG + 0) * SCAP;
        const uint2* e1 = ent + ((size_t)bt * NSEG + 1) * SCAP;
        const uint2* e2 = ent + ((size_t)bt * NSEG + 2) * SCAP;
        const uint2* e3 = ent + ((size_t)bt * NSEG + 3) * SCAP;
        if ((unsigned)tid < c0) elist[tid]      = e0[tid];
        if ((unsigned)tid < c1) elist[o1 + tid] = e1[tid];
        if ((unsigned)tid < c2) elist[o2 + tid] = e2[tid];
        if ((unsigned)tid < c3) elist[o3 + tid] = e3[tid];
    }
    __syncthreads();

    const int nb = (int)(count + 63) >> 6;

    f32x4 acc[4] = {{0.f,0.f,0.f,0.f},{0.f,0.f,0.f,0.f},
                    {0.f,0.f,0.f,0.f},{0.f,0.f,0.f,0.f}};

    for (int it = 0; it <= nb; ++it) {
        const int bb = it & 1;
        unsigned short* Wb = (unsigned short*)(smem + bb * 8192);
        unsigned short* Cv = (unsigned short*)(smem + 16384 + bb * 8192);
        if (it < nb) {                              // zero W (8 KB)
            uint4* wq = (uint4*)Wb;
            const uint4 z = make_uint4(0u, 0u, 0u, 0u);
            wq[tid] = z; wq[tid + 256] = z;
        }
        __syncthreads();   // zero visible; prior MFMA done reading buf bb

        unsigned short u[16];
        if (it < nb) {
            // ---- scatter bilinear weights: thread = (entry, corner) ----
            {
                const int eL = tid >> 2, cn = tid & 3;
                const unsigned idx = (unsigned)(it * 64 + eL);
                if (idx < count) {
                    const uint2 r = elist[idx];
                    const int lx = (int)((r.x >> 20) & 31) - 1 + (cn & 1);
                    const int ly = (int)((r.x >> 25) & 7) - 1 + (cn >> 1);
                    if (((unsigned)lx < TW) & ((unsigned)ly < TH)) {
                        const float dx = __half2float(__ushort_as_half((unsigned short)(r.y & 0xFFFF)));
                        const float dy = __half2float(__ushort_as_half((unsigned short)(r.y >> 16)));
                        const float wx = (cn & 1) ? dx : 1.f - dx;
                        const float wy = (cn >> 1) ? dy : 1.f - dy;
                        const int px = ly * TW + lx;
                        Wb[px * 64 + (eL ^ ((px & 7) << 3))] = f2h(wx * wy);
                    }
                }
            }
            // ---- issue CV loads (consumed after the MFMA block below) ----
            #pragma unroll
            for (int j = 0; j < 16; ++j) {
                const unsigned idx = (unsigned)(it * 64 + wv * 16 + j);
                unsigned short v = 0;
                if (idx < count) {
                    const unsigned row = elist[idx].x & 0xFFFFFu;
                    v = cb[((size_t)row << 6) + lane];
                }
                u[j] = v;
            }
        }
        if (it > 0) {
            // ---- MFMA on previous buffer: out[16px x 64ch] += W x CV ----
            const int pb = bb ^ 1;
            const unsigned short* Wp = (const unsigned short*)(smem + pb * 8192);
            const unsigned short* Cp = (const unsigned short*)(smem + 16384 + pb * 8192);
            const int m = lane & 15, kh = lane >> 4;
            const int px = wv * 16 + m;
            f16x8 af[2];
            #pragma unroll
            for (int kc = 0; kc < 2; ++kc)
                af[kc] = *(const f16x8*)(Wp + px * 64 + (((kc * 4 + kh) ^ (px & 7)) << 3));
            #pragma unroll
            for (int n = 0; n < 4; ++n) {
                const int ch = n * 16 + m;
                #pragma unroll
                for (int kc = 0; kc < 2; ++kc) {
                    const f16x8 bf = *(const f16x8*)(Cp + ch * 64 + (((kc * 4 + kh) ^ (ch & 7)) << 3));
                    acc[n] = __builtin_amdgcn_mfma_f32_16x16x32_f16(af[kc], bf, acc[n], 0, 0, 0);
                }
            }
        }
        if (it < nb) {
            // ---- pack staged CV rows into LDS (waits on the u[] loads) ----
            uint4* cvq = (uint4*)Cv;
            const uint4 pk0 = make_uint4(
                (unsigned)u[0]  | ((unsigned)u[1]  << 16),
                (unsigned)u[2]  | ((unsigned)u[3]  << 16),
                (unsigned)u[4]  | ((unsigned)u[5]  << 16),
                (unsigned)u[6]  | ((unsigned)u[7]  << 16));
            const uint4 pk1 = make_uint4(
                (unsigned)u[8]  | ((unsigned)u[9]  << 16),
                (unsigned)u[10] | ((unsigned)u[11] << 16),
                (unsigned)u[12] | ((unsigned)u[13] << 16),
                (unsigned)u[14] | ((unsigned)u[15] << 16));
            cvq[lane * 8 + ((wv * 2)     ^ (lane & 7))] = pk0;
            cvq[lane * 8 + ((wv * 2 + 1) ^ (lane & 7))] = pk1;
        }
        __syncthreads();   // build of buf bb complete; MFMA of bb^1 done
    }

    // ---- epilogue: transpose through LDS, coalesced store ----
    float* stage = (float*)smem;
    #pragma unroll
    for (int n = 0; n < 4; ++n) {
        #pragma unroll
        for (int r = 0; r < 4; ++r)
            stage[(wv * 16 + (lane >> 4) * 4 + r) * 65 + n * 16 + (lane & 15)] = acc[n][r];
    }
    __syncthreads();
    const int py = lane >> 4, pxx = lane & 15;
    const size_t q = (size_t)(ty0 + py) * OW + tx0 + pxx;
    #pragma unroll
    for (int j = 0; j < 16; ++j) {
        const int c = wv * 16 + j;
        out[(size_t)c * OHOW + q] = stage[(py * 16 + pxx) * 65 + c] + bias[c & 31];
    }
}

// ================= fallback (no ws requirement) ==============================
__global__ __launch_bounds__(576) void mtc_scatter_direct(
    const float* __restrict__ x, const float* __restrict__ weight,
    const float* __restrict__ smap, float* __restrict__ acc)
{
    __shared__ float xs[64][68];
    __shared__ float sm[64 * KK * 2];
    const int t = threadIdx.x;
    const int p0 = blockIdx.x * 64;
    if (t < 512) {
        const int pp = t & 63, c0 = t >> 6;
        #pragma unroll
        for (int ch = 0; ch < 8; ++ch) {
            const int c = c0 + ch * 8;
            xs[pp][c] = x[(size_t)c * PIX + p0 + pp];
        }
    }
    for (int i = t; i < 64 * KK * 2; i += 576)
        sm[i] = smap[(size_t)p0 * (KK * 2) + i];
    const int k = t >> 6, lane = t & 63, b = lane >> 5, o = lane & 31;
    float wreg[CIN];
    #pragma unroll
    for (int i = 0; i < CIN; ++i) wreg[i] = weight[(i * COUT + o) * KK + k];
    __syncthreads();
    for (int pp = 0; pp < 64; ++pp) {
        const float sx = sm[(pp * KK + k) * 2], sy = sm[(pp * KK + k) * 2 + 1];
        int x0, y0, x1, y1; float dx, dy;
        corners(sx, sy, x0, y0, x1, y1, dx, dy);
        const float* xrow = &xs[pp][b * 32];
        float cv = 0.f;
        #pragma unroll
        for (int j = 0; j < 8; ++j) {
            const float4 xv = *(const float4*)(xrow + 4 * j);
            cv += xv.x * wreg[4*j] + xv.y * wreg[4*j+1] + xv.z * wreg[4*j+2] + xv.w * wreg[4*j+3];
        }
        const size_t base = (size_t)lane * OHOW;
        atomicAdd(&acc[base + y0 * OW + x0], cv * (1.f - dx) * (1.f - dy));
        atomicAdd(&acc[base + y0 * OW + x1], cv * dx * (1.f - dy));
        atomicAdd(&acc[base + y1 * OW + x0], cv * (1.f - dx) * dy);
        atomicAdd(&acc[base + y1 * OW + x1], cv * dx * dy);
    }
}

__global__ __launch_bounds__(256) void mtc_bias_add(
    float* __restrict__ out, const float* __restrict__ bias)
{
    const size_t i = (size_t)blockIdx.x * 256 + threadIdx.x;
    out[i] += bias[(i >> 18) & 31];
}

extern "C" void kernel_launch(void* const* d_in, const int* in_sizes, int n_in,
                              void* d_out, int out_size, void* d_ws, size_t ws_size,
                              hipStream_t stream) {
    const float* x      = (const float*)d_in[0];
    const float* weight = (const float*)d_in[1];
    const float* bias   = (const float*)d_in[2];
    const float* smap   = (const float*)d_in[3];
    float* out = (float*)d_out;
    char* ws = (char*)d_ws;

    if (ws_size >= WS_NEED) {
        unsigned* cnt = (unsigned*)(ws + OFF_CNT);
        __bf16* wth   = (__bf16*)(ws + OFF_WT);
        __bf16* wtl   = wth + KK * COUT * CIN;
        uint2* ent    = (uint2*)(ws + OFF_ENT);
        unsigned short* cb = (unsigned short*)(ws + OFF_CB);

        hipMemsetAsync(cnt, 0, NSEG * NBIN * sizeof(unsigned), stream);
        k_wtb<<<(KK * COUT * CIN + 255) / 256, 256, 0, stream>>>(weight, wth, wtl);
        k_contrib5<<<PIX / 64, 256, 0, stream>>>(x, wth, wtl, smap, cb, cnt, ent);
        k_gather<<<NTILE, 256, 0, stream>>>(cb, ent, cnt, bias, out);
    } else {
        hipMemsetAsync(out, 0, (size_t)OHOW * NCH * sizeof(float), stream);
        mtc_scatter_direct<<<PIX / 64, 576, 0, stream>>>(x, weight, smap, out);
        mtc_bias_add<<<(OHOW * NCH) / 256, 256, 0, stream>>>(out, bias);
    }
}

// Round 7
// 166.948 us; speedup vs baseline: 1.6059x; 1.0155x over previous
//
#include <hip/hip_runtime.h>
#include <hip/hip_fp16.h>

#define CIN 32
#define COUT 32
#define KK 9
#define PIX 65536          // 256*256 input pixels
#define OH 512
#define OW 512
#define OHOW (OH*OW)
#define NCH 64             // B*COUT
#define TW 16              // tile width  (x)
#define TH 4               // tile height (y)
#define TPX (TW*TH)        // 64 px per tile
#define NTX (OW/TW)        // 32
#define NTY (OH/TH)        // 128
#define NTILE (NTX*NTY)    // 4096
#define NBIN NTILE         // per-tile bins
#define NPK (PIX*KK)       // 589824 (p,k) pairs
#define NSEG 4             // bins segmented by source blockIdx&3 (~XCD pairs)
#define SCAP 96            // per-(bin,seg) capacity; lambda~48, P(ovfl)~1e-4 grid-wide
#define CAPT (NSEG*SCAP)   // 384 entries per tile max

// ---- ws layout (bytes) ----
#define OFF_CNT 0                              // u32[NSEG][NBIN] 64 KB (seg-major)
#define OFF_WT  (256*1024)                     // bf16 hi[9216] + lo[9216] = 36.9 KB
#define OFF_ENT (512*1024)                     // uint2[NBIN*NSEG*SCAP]  12.6 MB
#define OFF_CB  (OFF_ENT + (size_t)NBIN*NSEG*SCAP*8) // f16[NPK*64] 75.5 MB
#define WS_NEED (OFF_CB + (size_t)NPK*NCH*2)   // ~88.6 MB

typedef __bf16    bf16x8 __attribute__((ext_vector_type(8)));
typedef _Float16  f16x8  __attribute__((ext_vector_type(8)));
typedef float     f32x4  __attribute__((ext_vector_type(4)));

__device__ __forceinline__ unsigned short f2h(float v)
{
    return __half_as_ushort(__float2half_rn(v));
}

// corner setup (clips never fire for this input; kept for safety)
__device__ __forceinline__ void corners(float sx, float sy,
    int& x0, int& y0, int& x1, int& y1, float& dx, float& dy)
{
    const float x0f = floorf(sx), y0f = floorf(sy);
    dx = sx - x0f; dy = sy - y0f;
    x0 = min(max((int)x0f, 0), OW - 1);
    y0 = min(max((int)y0f, 0), OH - 1);
    x1 = min(x0 + 1, OW - 1);
    y1 = min(y0 + 1, OH - 1);
}

// ============ pass 0: zero cnt + W[i][o][k] -> bf16 hi/lo [k][o][i] ==========
// 64 blocks x 256 = 16384 threads: one thread per counter; first 9216 also
// transform a weight. Replaces hipMemsetAsync + k_wtb (one fewer dispatch).
__global__ __launch_bounds__(256) void k_init(
    const float* __restrict__ w, __bf16* __restrict__ wth,
    __bf16* __restrict__ wtl, unsigned* __restrict__ cnt)
{
    const int t = blockIdx.x * 256 + threadIdx.x;
    if (t < NSEG * NBIN) cnt[t] = 0;
    if (t < KK * COUT * CIN) {
        const int i = t & 31;
        const int o = (t >> 5) & 31;
        const int k = t >> 10;
        const float v = w[(i * COUT + o) * KK + k];
        const __bf16 h = (__bf16)v;
        wth[t] = h;
        wtl[t] = (__bf16)(v - (float)h);
    }
}

// ============ pass 1: contrib via MFMA + seg-local deferred binning ==========
// (round-5 body, unchanged: 52 us, WRITE 117 MB, the control this round)
__global__ __launch_bounds__(256, 1) void k_contrib5(
    const float* __restrict__ x, const __bf16* __restrict__ wth,
    const __bf16* __restrict__ wtl, const float* __restrict__ smap,
    unsigned short* __restrict__ cb, unsigned* __restrict__ cnt,
    uint2* __restrict__ ent)
{
    __shared__ __align__(16) unsigned short patch[4][2][16][72]; // 18.4 KB
    const int tid = threadIdx.x, lane = tid & 63;
    const int wu = __builtin_amdgcn_readfirstlane(tid >> 6);   // uniform wave id
    const int p0 = blockIdx.x * 64;
    const unsigned seg = blockIdx.x & 3;
    const int colp = lane & 15;          // px within wave / o within 16 / B-col
    const int q    = lane >> 4;          // k-chunk quad
    const int cig  = q * 8;              // ci base for MFMA fragments

    // ---- x fragments first (ahead of atomics; vmcnt is in-order) ----
    bf16x8 xh[2], xl[2];
    #pragma unroll
    for (int b = 0; b < 2; ++b) {
        const int p = p0 + wu * 16 + colp;
        #pragma unroll
        for (int j = 0; j < 8; ++j) {
            const float v = x[(size_t)(b * 32 + cig + j) * PIX + p];
            const __bf16 h = (__bf16)v;
            xh[b][j] = h;
            xl[b][j] = (__bf16)(v - (float)h);
        }
    }
    bf16x8 wwh[2][2], wwl[2][2];         // [buf][oh]
    #pragma unroll
    for (int oh = 0; oh < 2; ++oh) {
        wwh[0][oh] = *(const bf16x8*)(wth + (oh * 16 + colp) * 32 + cig);
        wwl[0][oh] = *(const bf16x8*)(wtl + (oh * 16 + colp) * 32 + cig);
    }

    // ---- binning; atomics fired last, returns consumed at the end ----
    unsigned aS[3][4], aA[3][4], aR[3][4], aW[3];
    #pragma unroll
    for (int it = 0; it < 3; ++it) {
        const int idx = tid + it * 256;
        const bool vit = idx < 576;
        const int t = min(p0 * KK + idx, NPK - 1);
        const float sx = smap[2 * t], sy = smap[2 * t + 1];
        int x0, y0, x1, y1; float dx, dy;
        corners(sx, sy, x0, y0, x1, y1, dx, dy);
        const int g0 = x0 >> 4, g1 = x1 >> 4;   // tile col
        const int t0 = y0 >> 2, t1 = y1 >> 2;   // tile row
        aW[it] = (unsigned)f2h(dx) | ((unsigned)f2h(dy) << 16);
        const bool dg = (g1 != g0), dt = (t1 != t0);
        const bool cond[4] = { vit, vit && dg, vit && dt, vit && dg && dt };
        const int  tys[4]  = { t0, t0, t1, t1 };
        const int  gss[4]  = { g0, g1, g0, g1 };
        #pragma unroll
        for (int e = 0; e < 4; ++e) {
            unsigned slot = 0xFFFFFFFFu;
            const int bin = tys[e] * 32 + gss[e];
            const unsigned lxb = (unsigned)(x0 - gss[e] * TW + 1);
            const unsigned lyb = (unsigned)(y0 - tys[e] * TH + 1);
            if (cond[e]) slot = atomicAdd(&cnt[seg * NBIN + bin], 1u);
            aS[it][e] = slot;
            aA[it][e] = ((unsigned)bin * NSEG + seg) * SCAP;
            aR[it][e] = (unsigned)t | (lxb << 20) | (lyb << 25);
        }
    }

    // ---- k-loop: MFMA -> per-wave LDS patch -> full-sector stores ----
    const int pxr = lane >> 2, cc = lane & 3;   // flush mapping
    #pragma unroll
    for (int k = 0; k < KK; ++k) {
        const int kb = k & 1;
        const int cur = k & 1, nxt = cur ^ 1;
        if (k + 1 < KK) {                       // prefetch W(k+1)
            const __bf16* wb = wth + (k + 1) * (COUT * CIN);
            const __bf16* lb = wtl + (k + 1) * (COUT * CIN);
            #pragma unroll
            for (int oh = 0; oh < 2; ++oh) {
                wwh[nxt][oh] = *(const bf16x8*)(wb + (oh * 16 + colp) * 32 + cig);
                wwl[nxt][oh] = *(const bf16x8*)(lb + (oh * 16 + colp) * 32 + cig);
            }
        }
        #pragma unroll
        for (int cg_ = 0; cg_ < 4; ++cg_) {     // ch group: b=cg>>1, oh=cg&1
            const int b = cg_ >> 1, oh = cg_ & 1;
            f32x4 a = {0.f, 0.f, 0.f, 0.f};
            a = __builtin_amdgcn_mfma_f32_16x16x32_bf16(wwh[cur][oh], xh[b], a, 0, 0, 0);
            a = __builtin_amdgcn_mfma_f32_16x16x32_bf16(wwl[cur][oh], xh[b], a, 0, 0, 0);
            a = __builtin_amdgcn_mfma_f32_16x16x32_bf16(wwh[cur][oh], xl[b], a, 0, 0, 0);
            const unsigned d0 = (unsigned)f2h(a[0]) | ((unsigned)f2h(a[1]) << 16);
            const unsigned d1 = (unsigned)f2h(a[2]) | ((unsigned)f2h(a[3]) << 16);
            *(uint2*)&patch[wu][kb][colp][cg_ * 16 + q * 4] = make_uint2(d0, d1);
        }
        const uint4 a0 = *(const uint4*)&patch[wu][kb][pxr][cc * 8];
        const uint4 a1 = *(const uint4*)&patch[wu][kb][pxr][32 + cc * 8];
        unsigned short* dst = cb + (size_t)(p0 + wu * 16 + pxr) * 576 + k * 64 + cc * 8;
        *(uint4*)dst        = a0;               // 4 lanes = 64B contiguous sector
        *(uint4*)(dst + 32) = a1;
    }

    // ---- deferred ent stores (atomic returns long-arrived) ----
    #pragma unroll
    for (int it = 0; it < 3; ++it) {
        #pragma unroll
        for (int e = 0; e < 4; ++e) {
            if (aS[it][e] < SCAP)
                ent[(size_t)aA[it][e] + aS[it][e]] = make_uint2(aR[it][e], aW[it]);
        }
    }
}

// ---- gather helpers ----
// load 16 CV rows (this wave's entries [b*64+wv*16, +16)) into named regs
#define LOADU(UU, ITb) { \
    _Pragma("unroll") \
    for (int j = 0; j < 16; ++j) { \
        const unsigned idx = (unsigned)((ITb) * 64 + wv * 16 + j); \
        unsigned short v = 0; \
        if (idx < count) \
            v = cb[((size_t)(elist[idx].x & 0xFFFFFu) << 6) + lane]; \
        UU[j] = v; \
    } }

// one batch of 64 entries: zero W, scatter bilinear weights, pack CV (from
// statically-indexed regs UU), 8 MFMAs into acc[]. Single W/CV buffer.
#define BATCH_BODY(ITc, UU) { \
    { uint4* wq = (uint4*)Wb; const uint4 z = make_uint4(0u,0u,0u,0u); \
      wq[tid] = z; wq[tid + 256] = z; } \
    __syncthreads(); \
    { const int eL = tid >> 2, cn = tid & 3; \
      const unsigned idx = (unsigned)((ITc) * 64 + eL); \
      if (idx < count) { \
        const uint2 r = elist[idx]; \
        const int lx = (int)((r.x >> 20) & 31) - 1 + (cn & 1); \
        const int ly = (int)((r.x >> 25) & 7) - 1 + (cn >> 1); \
        if (((unsigned)lx < TW) & ((unsigned)ly < TH)) { \
            const float dx = __half2float(__ushort_as_half((unsigned short)(r.y & 0xFFFF))); \
            const float dy = __half2float(__ushort_as_half((unsigned short)(r.y >> 16))); \
            const float wx = (cn & 1) ? dx : 1.f - dx; \
            const float wy = (cn >> 1) ? dy : 1.f - dy; \
            const int px = ly * TW + lx; \
            Wb[px * 64 + (eL ^ ((px & 7) << 3))] = f2h(wx * wy); \
        } } } \
    { uint4* cvq = (uint4*)Cv; \
      const uint4 pk0 = make_uint4( \
        (unsigned)UU[0]  | ((unsigned)UU[1]  << 16), (unsigned)UU[2]  | ((unsigned)UU[3]  << 16), \
        (unsigned)UU[4]  | ((unsigned)UU[5]  << 16), (unsigned)UU[6]  | ((unsigned)UU[7]  << 16)); \
      const uint4 pk1 = make_uint4( \
        (unsigned)UU[8]  | ((unsigned)UU[9]  << 16), (unsigned)UU[10] | ((unsigned)UU[11] << 16), \
        (unsigned)UU[12] | ((unsigned)UU[13] << 16), (unsigned)UU[14] | ((unsigned)UU[15] << 16)); \
      cvq[lane * 8 + ((wv * 2)     ^ (lane & 7))] = pk0; \
      cvq[lane * 8 + ((wv * 2 + 1) ^ (lane & 7))] = pk1; } \
    __syncthreads(); \
    { const int m = lane & 15, kh = lane >> 4; \
      const int px = wv * 16 + m; \
      const f16x8 af0 = *(const f16x8*)(Wb + px * 64 + ((kh       ^ (px & 7)) << 3)); \
      const f16x8 af1 = *(const f16x8*)(Wb + px * 64 + (((4 + kh) ^ (px & 7)) << 3)); \
      _Pragma("unroll") \
      for (int n = 0; n < 4; ++n) { \
        const int ch = n * 16 + m; \
        const f16x8 bf0 = *(const f16x8*)(Cv + ch * 64 + ((kh       ^ (ch & 7)) << 3)); \
        acc[n] = __builtin_amdgcn_mfma_f32_16x16x32_f16(af0, bf0, acc[n], 0, 0, 0); \
        const f16x8 bf1 = *(const f16x8*)(Cv + ch * 64 + (((4 + kh) ^ (ch & 7)) << 3)); \
        acc[n] = __builtin_amdgcn_mfma_f32_16x16x32_f16(af1, bf1, acc[n], 0, 0, 0); } } \
    __syncthreads(); }

// ============ pass 2: batched-MFMA gather, all-batches CV prefetch ===========
// Per tile: merge the 4 segment lists into LDS, then issue ALL (<=4 batches)
// CV loads into named register arrays up-front -> one memory round trip per
// tile instead of one per batch. Single W/CV buffer (loads are off the
// critical path); 3 block barriers per batch; rare tail uses inline loads.
__global__ __launch_bounds__(256) void k_gather(
    const unsigned short* __restrict__ cb, const uint2* __restrict__ ent,
    const unsigned* __restrict__ cnt, const float* __restrict__ bias,
    float* __restrict__ out)
{
    __shared__ __align__(16) unsigned char smem[16640]; // W+CV / f32 stage[64][65]
    __shared__ __align__(16) uint2 elist[CAPT];         // 3 KB merged entry list
    unsigned short* Wb = (unsigned short*)smem;          // f16 [64px][64e], swz by px&7
    unsigned short* Cv = (unsigned short*)(smem + 8192); // f16 [64ch][64e], swz by ch&7
    const int tid = threadIdx.x, lane = tid & 63;
    const int wv = __builtin_amdgcn_readfirstlane(tid >> 6);   // wave id 0..3
    const int bt = blockIdx.x;
    const int tx0 = (bt & 31) * TW;
    const int ty0 = (bt >> 5) * TH;

    // ---- merge segment lists into LDS ----
    const unsigned c0 = min(cnt[0 * NBIN + bt], (unsigned)SCAP);
    const unsigned c1 = min(cnt[1 * NBIN + bt], (unsigned)SCAP);
    const unsigned c2 = min(cnt[2 * NBIN + bt], (unsigned)SCAP);
    const unsigned c3 = min(cnt[3 * NBIN + bt], (unsigned)SCAP);
    const unsigned o1 = c0, o2 = c0 + c1, o3 = o2 + c2;
    const unsigned count = o3 + c3;
    {
        const uint2* e0 = ent + ((size_t)bt * NSEG + 0) * SCAP;
        const uint2* e1 = ent + ((size_t)bt * NSEG + 1) * SCAP;
        const uint2* e2 = ent + ((size_t)bt * NSEG + 2) * SCAP;
        const uint2* e3 = ent + ((size_t)bt * NSEG + 3) * SCAP;
        if ((unsigned)tid < c0) elist[tid]      = e0[tid];
        if ((unsigned)tid < c1) elist[o1 + tid] = e1[tid];
        if ((unsigned)tid < c2) elist[o2 + tid] = e2[tid];
        if ((unsigned)tid < c3) elist[o3 + tid] = e3[tid];
    }
    __syncthreads();

    const int nb = (int)(count + 63) >> 6;

    // ---- prefetch ALL (<=4) batches' CV rows into named register arrays ----
    unsigned short uA[16], uB[16], uC[16], uD[16];
    LOADU(uA, 0); LOADU(uB, 1); LOADU(uC, 2); LOADU(uD, 3);

    f32x4 acc[4] = {{0.f,0.f,0.f,0.f},{0.f,0.f,0.f,0.f},
                    {0.f,0.f,0.f,0.f},{0.f,0.f,0.f,0.f}};

    if (0 < nb) { BATCH_BODY(0, uA); }
    if (1 < nb) { BATCH_BODY(1, uB); }
    if (2 < nb) { BATCH_BODY(2, uC); }
    if (3 < nb) { BATCH_BODY(3, uD); }
    // rare tail (count > 256): inline loads
    for (int it = 4; it < nb; ++it) {
        unsigned short ut[16];
        LOADU(ut, it);
        BATCH_BODY(it, ut);
    }

    // ---- epilogue: transpose through LDS, coalesced store ----
    float* stage = (float*)smem;             // 16640 B, overlays W/CV
    #pragma unroll
    for (int n = 0; n < 4; ++n) {
        #pragma unroll
        for (int r = 0; r < 4; ++r)
            stage[(wv * 16 + (lane >> 4) * 4 + r) * 65 + n * 16 + (lane & 15)] = acc[n][r];
    }
    __syncthreads();
    const int py = lane >> 4, pxx = lane & 15;
    const size_t qq = (size_t)(ty0 + py) * OW + tx0 + pxx;
    #pragma unroll
    for (int j = 0; j < 16; ++j) {
        const int c = wv * 16 + j;
        out[(size_t)c * OHOW + qq] = stage[(py * 16 + pxx) * 65 + c] + bias[c & 31];
    }
}

// ================= fallback (no ws requirement) ==============================
__global__ __launch_bounds__(576) void mtc_scatter_direct(
    const float* __restrict__ x, const float* __restrict__ weight,
    const float* __restrict__ smap, float* __restrict__ acc)
{
    __shared__ float xs[64][68];
    __shared__ float sm[64 * KK * 2];
    const int t = threadIdx.x;
    const int p0 = blockIdx.x * 64;
    if (t < 512) {
        const int pp = t & 63, c0 = t >> 6;
        #pragma unroll
        for (int ch = 0; ch < 8; ++ch) {
            const int c = c0 + ch * 8;
            xs[pp][c] = x[(size_t)c * PIX + p0 + pp];
        }
    }
    for (int i = t; i < 64 * KK * 2; i += 576)
        sm[i] = smap[(size_t)p0 * (KK * 2) + i];
    const int k = t >> 6, lane = t & 63, b = lane >> 5, o = lane & 31;
    float wreg[CIN];
    #pragma unroll
    for (int i = 0; i < CIN; ++i) wreg[i] = weight[(i * COUT + o) * KK + k];
    __syncthreads();
    for (int pp = 0; pp < 64; ++pp) {
        const float sx = sm[(pp * KK + k) * 2], sy = sm[(pp * KK + k) * 2 + 1];
        int x0, y0, x1, y1; float dx, dy;
        corners(sx, sy, x0, y0, x1, y1, dx, dy);
        const float* xrow = &xs[pp][b * 32];
        float cv = 0.f;
        #pragma unroll
        for (int j = 0; j < 8; ++j) {
            const float4 xv = *(const float4*)(xrow + 4 * j);
            cv += xv.x * wreg[4*j] + xv.y * wreg[4*j+1] + xv.z * wreg[4*j+2] + xv.w * wreg[4*j+3];
        }
        const size_t base = (size_t)lane * OHOW;
        atomicAdd(&acc[base + y0 * OW + x0], cv * (1.f - dx) * (1.f - dy));
        atomicAdd(&acc[base + y0 * OW + x1], cv * dx * (1.f - dy));
        atomicAdd(&acc[base + y1 * OW + x0], cv * (1.f - dx) * dy);
        atomicAdd(&acc[base + y1 * OW + x1], cv * dx * dy);
    }
}

__global__ __launch_bounds__(256) void mtc_bias_add(
    float* __restrict__ out, const float* __restrict__ bias)
{
    const size_t i = (size_t)blockIdx.x * 256 + threadIdx.x;
    out[i] += bias[(i >> 18) & 31];
}

extern "C" void kernel_launch(void* const* d_in, const int* in_sizes, int n_in,
                              void* d_out, int out_size, void* d_ws, size_t ws_size,
                              hipStream_t stream) {
    const float* x      = (const float*)d_in[0];
    const float* weight = (const float*)d_in[1];
    const float* bias   = (const float*)d_in[2];
    const float* smap   = (const float*)d_in[3];
    float* out = (float*)d_out;
    char* ws = (char*)d_ws;

    if (ws_size >= WS_NEED) {
        unsigned* cnt = (unsigned*)(ws + OFF_CNT);
        __bf16* wth   = (__bf16*)(ws + OFF_WT);
        __bf16* wtl   = wth + KK * COUT * CIN;
        uint2* ent    = (uint2*)(ws + OFF_ENT);
        unsigned short* cb = (unsigned short*)(ws + OFF_CB);

        k_init<<<64, 256, 0, stream>>>(weight, wth, wtl, cnt);
        k_contrib5<<<PIX / 64, 256, 0, stream>>>(x, wth, wtl, smap, cb, cnt, ent);
        k_gather<<<NTILE, 256, 0, stream>>>(cb, ent, cnt, bias, out);
    } else {
        hipMemsetAsync(out, 0, (size_t)OHOW * NCH * sizeof(float), stream);
        mtc_scatter_direct<<<PIX / 64, 576, 0, stream>>>(x, weight, smap, out);
        mtc_bias_add<<<(OHOW * NCH) / 256, 256, 0, stream>>>(out, bias);
    }
}